// Round 6
// baseline (4698.760 us; speedup 1.0000x reference)
//
#include <hip/hip_runtime.h>
#include <math.h>

// Problem constants
static constexpr int BB = 64, TT = 26, EE = 300, HH = 1024;
static constexpr int FEAT = 2048, SS = 49;
static constexpr int D1 = 245000, D2 = 5000;
static constexpr int MOUT = 1000;
static constexpr int VOCAB = 3000;

static constexpr int PAD1T = 2048;               // mod-free pad rows (span <= 245*7+1 = 1716)
static constexpr int NROWS = D1 + PAD1T;         // 247048 rows in transposed sketch
static constexpr int FOLD_R = 16000;
static constexpr int FOLD_NR = 16;
static constexpr int NITEMS = FEAT * SS;         // 100352
static constexpr int NP = 10;                    // gather phases
static constexpr int WP = 24500;                 // phase window (bins); WP*NP = D1
static constexpr int LSTM_BLOCKS = 256;

// ---------------------------------------------------------------------------
// Generic fp32 GEMM: C[M,N] = act( A(M,K) * B(N,K)^T + bias1 + bias2 )
// ---------------------------------------------------------------------------
template <int BM, int BN, int BK, int TM, int TN, bool RELU>
__global__ void gemm_abt(const float* __restrict__ A, const float* __restrict__ B,
                         const float* __restrict__ bias1, const float* __restrict__ bias2,
                         float* __restrict__ C,
                         int M, int N, int K, int lda, int ldb, int ldc) {
    constexpr int THREADS = (BM / TM) * (BN / TN);
    __shared__ float As[BK][BM + 1];
    __shared__ float Bs[BK][BN + 1];
    const int tid = threadIdx.x;
    const int tx = tid % (BN / TN);
    const int ty = tid / (BN / TN);
    const int block_m = blockIdx.y * BM;
    const int block_n = blockIdx.x * BN;
    float acc[TM][TN];
#pragma unroll
    for (int i = 0; i < TM; i++)
#pragma unroll
        for (int j = 0; j < TN; j++) acc[i][j] = 0.f;

    for (int k0 = 0; k0 < K; k0 += BK) {
        for (int i = tid; i < BM * BK; i += THREADS) {
            int m = i / BK, kk = i % BK;
            int gm = block_m + m, gk = k0 + kk;
            As[kk][m] = (gm < M && gk < K) ? A[(size_t)gm * lda + gk] : 0.f;
        }
        for (int i = tid; i < BN * BK; i += THREADS) {
            int n = i / BK, kk = i % BK;
            int gn = block_n + n, gk = k0 + kk;
            Bs[kk][n] = (gn < N && gk < K) ? B[(size_t)gn * ldb + gk] : 0.f;
        }
        __syncthreads();
#pragma unroll
        for (int kk = 0; kk < BK; kk++) {
            float a[TM], b[TN];
#pragma unroll
            for (int i = 0; i < TM; i++) a[i] = As[kk][ty * TM + i];
#pragma unroll
            for (int j = 0; j < TN; j++) b[j] = Bs[kk][tx * TN + j];
#pragma unroll
            for (int i = 0; i < TM; i++)
#pragma unroll
                for (int j = 0; j < TN; j++) acc[i][j] += a[i] * b[j];
        }
        __syncthreads();
    }
#pragma unroll
    for (int i = 0; i < TM; i++) {
        int gm = block_m + ty * TM + i;
        if (gm >= M) continue;
#pragma unroll
        for (int j = 0; j < TN; j++) {
            int gn = block_n + tx * TN + j;
            if (gn >= N) continue;
            float v = acc[i][j];
            if (bias1) v += bias1[gn];
            if (bias2) v += bias2[gn];
            if (RELU) v = fmaxf(v, 0.f);
            C[(size_t)gm * ldc + gn] = v;
        }
    }
}

// ---------------------------------------------------------------------------
// xw transpose: xw[(b*T+t), g] -> xwT[(t*4096+g)*64 + b]
// ---------------------------------------------------------------------------
__global__ void xwt_transpose(const float* __restrict__ xw, float* __restrict__ xwT) {
    __shared__ float L[64][65];
    const int t = blockIdx.x;
    const int g0 = blockIdx.y * 64;
    const int tid = threadIdx.x;
    for (int u = 0; u < 16; u++) {
        int idx = u * 256 + tid;
        int b = idx >> 6, g = idx & 63;
        L[g][b] = xw[((size_t)b * TT + t) * 4096 + g0 + g];
    }
    __syncthreads();
    for (int u = 0; u < 16; u++) {
        int idx = u * 256 + tid;
        int g = idx >> 6, b = idx & 63;
        xwT[((size_t)t * 4096 + g0 + g) * 64 + b] = L[g][b];
    }
}

// ---------------------------------------------------------------------------
// Persistent LSTM v3: 256 blocks (1/CU). Block owns 4 hidden slots x 4 gates.
// h written to a fresh ring slot each step (hR[step]) => consumers' first
// touch after the barrier misses L2 and pulls fresh data from L3. NO acquire
// (no L2 invalidate) => W_hh slice stays XCD-L2-resident across all steps.
// Producer release-add writes back dirty lines only. 8-counter barrier.
// Register-prefetch pipeline overlaps h-chunk loads with FMA.
// ---------------------------------------------------------------------------
__global__ void __launch_bounds__(256, 1)
lstm_persist3(const float* __restrict__ xwT, const float* __restrict__ W_hh,
              float* __restrict__ hs, float* __restrict__ hR,
              unsigned* __restrict__ bar) {
    __shared__ float hl[8192];           // 128 k x 64 b (32 KB)
    __shared__ float part[4][4][64];     // [gate][hh_loc][b]
    const int tid = threadIdx.x;
    const int b = tid & 63;
    const int jw = __builtin_amdgcn_readfirstlane(tid >> 6);   // wave id = gate
    const int hh0 = blockIdx.x * 4;
    const int i_p = tid >> 6;
    float creg = 0.f;

    const float* __restrict__ Wbase = W_hh + ((size_t)jw * 1024 + hh0) * 1024;

    for (int step = 0; step < TT; step++) {
        if (step > 0) {
            const float* __restrict__ hTc = hR + (size_t)(step - 1) * 65536;
            float4 pf[8];
            {
                const float4* src = (const float4*)hTc;
#pragma unroll
                for (int u = 0; u < 8; u++) pf[u] = src[u * 256 + tid];
            }
            float acc0 = 0.f, acc1 = 0.f, acc2 = 0.f, acc3 = 0.f;
            for (int c = 0; c < 8; c++) {
                __syncthreads();                         // prior chunk consumed
                {
                    float4* dst = (float4*)hl;
#pragma unroll
                    for (int u = 0; u < 8; u++) dst[u * 256 + tid] = pf[u];
                }
                __syncthreads();                         // hl ready
                if (c < 7) {                             // prefetch next chunk
                    const float4* src = (const float4*)(hTc + (c + 1) * 8192);
#pragma unroll
                    for (int u = 0; u < 8; u++) pf[u] = src[u * 256 + tid];
                }
                const float* __restrict__ Wr = Wbase + c * 128;
#pragma unroll 4
                for (int kk = 0; kk < 128; kk++) {
                    float hv = hl[kk * 64 + b];
                    acc0 = fmaf(Wr[kk], hv, acc0);
                    acc1 = fmaf(Wr[kk + 1024], hv, acc1);
                    acc2 = fmaf(Wr[kk + 2048], hv, acc2);
                    acc3 = fmaf(Wr[kk + 3072], hv, acc3);
                }
            }
            part[jw][0][b] = acc0;
            part[jw][1][b] = acc1;
            part[jw][2][b] = acc2;
            part[jw][3][b] = acc3;
            __syncthreads();
        }
        // pointwise: thread (i_p, b) owns hidden slot hh0+i_p, batch b
        {
            int row = hh0 + i_p;
            float g4[4];
#pragma unroll
            for (int j = 0; j < 4; j++) {
                float sum = xwT[((size_t)step * 4096 + j * 1024 + row) * 64 + b];
                if (step > 0) sum += part[j][i_p][b];
                g4[j] = sum;
            }
            float si = 1.f / (1.f + expf(-g4[0]));
            float sf = 1.f / (1.f + expf(-g4[1]));
            float tg = tanhf(g4[2]);
            float so = 1.f / (1.f + expf(-g4[3]));
            creg = sf * creg + si * tg;
            float hn = so * tanhf(creg);
            hR[(size_t)step * 65536 + row * 64 + b] = hn;
            hs[((size_t)step * BB + b) * HH + row] = hn;
        }
        if (step < TT - 1) {
            __syncthreads();
            if (tid == 0) {
                __hip_atomic_fetch_add(&bar[(blockIdx.x & 7) * 32], 1u,
                                       __ATOMIC_RELEASE, __HIP_MEMORY_SCOPE_AGENT);
                const unsigned target = 256u * (unsigned)(step + 1);
                for (;;) {
                    unsigned sum = 0;
#pragma unroll
                    for (int i = 0; i < 8; i++)
                        sum += __hip_atomic_load(&bar[i * 32], __ATOMIC_RELAXED,
                                                 __HIP_MEMORY_SCOPE_AGENT);
                    if (sum >= target) break;
                    __builtin_amdgcn_s_sleep(2);
                }
            }
            __syncthreads();
        }
    }
}

__global__ void qa2_kernel(const float* __restrict__ qa, const float* __restrict__ Wq2,
                           const float* __restrict__ bq2, float* __restrict__ out) {
    int tid = blockIdx.x * blockDim.x + threadIdx.x;
    if (tid >= BB * 2 * TT) return;
    int t = tid % TT;
    int bg = tid / TT;
    int g = bg & 1;
    const float* arow = qa + ((size_t)t * BB + (bg >> 1)) * 512;
    const float* wrow = Wq2 + g * 512;
    float acc = bq2[g];
    for (int o = 0; o < 512; o++) acc += wrow[o] * arow[o];
    out[tid] = acc;
}

__global__ void ia2_kernel(const float* __restrict__ ia, const float* __restrict__ Wi2,
                           const float* __restrict__ bi2, float* __restrict__ out) {
    int tid = blockIdx.x * blockDim.x + threadIdx.x;
    if (tid >= BB * 2 * SS) return;
    int s = tid % SS;
    int bg = tid / SS;
    int g = bg & 1;
    int b = bg >> 1;
    const float* arow = ia + ((size_t)b * SS + s) * 512;
    const float* wrow = Wi2 + g * 512;
    float acc = bi2[g];
    for (int o = 0; o < 512; o++) acc += wrow[o] * arow[o];
    out[tid] = acc;
}

__global__ void softmax_small(float* __restrict__ x, int rows, int len) {
    int r = blockIdx.x * blockDim.x + threadIdx.x;
    if (r >= rows) return;
    float* xr = x + (size_t)r * len;
    float mx = -1e30f;
    for (int i = 0; i < len; i++) mx = fmaxf(mx, xr[i]);
    float s = 0.f;
    for (int i = 0; i < len; i++) s += expf(xr[i] - mx);
    float inv = 1.f / s;
    for (int i = 0; i < len; i++) xr[i] = expf(xr[i] - mx) * inv;
}

__global__ void qfeat_kernel(const float* __restrict__ qatt, const float* __restrict__ hs,
                             float* __restrict__ qf) {
    int idx = blockIdx.x * blockDim.x + threadIdx.x;
    if (idx >= BB * 2048) return;
    int b = idx >> 11;
    int gh = idx & 2047;
    int g = gh >> 10;
    int hh = gh & 1023;
    float acc = 0.f;
    for (int t = 0; t < TT; t++)
        acc += qatt[((size_t)b * 2 + g) * TT + t] * hs[((size_t)t * BB + b) * HH + hh];
    qf[idx] = acc;
}

// ---------------------------------------------------------------------------
// MCB1 stage A: LDS-privatized scatter + FACTOR fold -> afold[b][t] fp32
// ---------------------------------------------------------------------------
__global__ void sketch_fold(const float* __restrict__ img_feat, const int* __restrict__ h1x,
                            const int* __restrict__ s1x, float* __restrict__ afold) {
    __shared__ float sl[FOLD_R + 196];
    const int b = blockIdx.y;
    const int r0 = blockIdx.x * FOLD_R;
    for (int i = threadIdx.x; i < FOLD_R + 196; i += 256) sl[i] = 0.f;
    __syncthreads();
    for (int i = threadIdx.x; i < NITEMS; i += 256) {
        int h = h1x[i];
        int d = h - r0;
        if (d < 0) d += D1;
        if (d < FOLD_R + 196) {
            int f = i / SS, s = i - f * SS;
            float val = img_feat[((size_t)b * SS + s) * FEAT + f]
                        * (float)(2 * s1x[i] - 1);
            atomicAdd(&sl[d], val);
        }
    }
    __syncthreads();
    float* ab = afold + (size_t)b * D1;
    for (int t = threadIdx.x; t < FOLD_R; t += 256) {
        int g = r0 + t;
        if (g >= D1) break;
        ab[g] = sl[t] + sl[t + 49] + sl[t + 98] + sl[t + 147] + sl[t + 196];
    }
}

__device__ __forceinline__ unsigned short bf16_rne(float x) {
    unsigned u = __float_as_uint(x);
    u += 0x7fffu + ((u >> 16) & 1u);
    return (unsigned short)(u >> 16);
}

// ---------------------------------------------------------------------------
// MCB1 stage B: transpose afold[b][t] -> atT[t][32 x bf16x2], with wrap pad.
// ---------------------------------------------------------------------------
__global__ void transpose_bf16(const float* __restrict__ afold, unsigned* __restrict__ atT) {
    __shared__ float L[64][65];
    const int t0 = blockIdx.x * 64;
    const int tid = threadIdx.x;
    for (int c = 0; c < 16; c++) {
        int idx = c * 256 + tid;          // b*64 + i
        int b = idx >> 6, i = idx & 63;
        int t = t0 + i;
        int src_t = (t < D1) ? t : t - D1;
        L[i][b] = afold[(size_t)b * D1 + src_t];
    }
    __syncthreads();
    for (int c = 0; c < 8; c++) {
        int u = c * 256 + tid;            // t_loc*32 + qq
        int t_loc = u >> 5, qq = u & 31;
        int t = t0 + t_loc;
        if (t >= NROWS) continue;
        unsigned lo = bf16_rne(L[t_loc][2 * qq]);
        unsigned hi = bf16_rne(L[t_loc][2 * qq + 1]);
        atT[(size_t)t * 32 + qq] = lo | (hi << 16);
    }
}

// ---------------------------------------------------------------------------
// Bitonic sort of (h1q, index), 2048 elements, one block of 1024 threads.
// ---------------------------------------------------------------------------
__global__ void sort_pv(const int* __restrict__ h1q, int* __restrict__ pS,
                        int* __restrict__ permS) {
    __shared__ int k[2048], v[2048];
    const int t = threadIdx.x;
    k[t] = h1q[t];          v[t] = t;
    k[t + 1024] = h1q[t + 1024]; v[t + 1024] = t + 1024;
    for (int size = 2; size <= 2048; size <<= 1) {
        for (int stride = size >> 1; stride > 0; stride >>= 1) {
            __syncthreads();
            int pos = 2 * t - (t & (stride - 1));
            bool asc = ((pos & size) == 0);
            int a = k[pos], b = k[pos + stride];
            if ((a > b) == asc) {
                k[pos] = b; k[pos + stride] = a;
                int tmp = v[pos]; v[pos] = v[pos + stride]; v[pos + stride] = tmp;
            }
        }
    }
    __syncthreads();
    pS[t] = k[t]; pS[t + 1024] = k[t + 1024];
    permS[t] = v[t]; permS[t + 1024] = v[t + 1024];
}

// vTs[r][q] = pack_bf16( qf[2q][j]*sgn[j], qf[2q+1][j]*sgn[j] ), j = permS[r]
__global__ void vts_build(const float* __restrict__ qf, const int* __restrict__ s1q,
                          const int* __restrict__ permS, unsigned* __restrict__ vTs) {
    int gid = blockIdx.x * blockDim.x + threadIdx.x;
    if (gid >= 2048 * 32) return;
    int r = gid >> 5, q = gid & 31;
    int j = permS[r];
    float sg = (float)(2 * s1q[j] - 1);
    unsigned lo = bf16_rne(qf[(size_t)(2 * q) * 2048 + j] * sg);
    unsigned hi = bf16_rne(qf[(size_t)(2 * q + 1) * 2048 + j] * sg);
    vTs[gid] = lo | (hi << 16);
}

__device__ __forceinline__ int lbound(const int* a, int x) {
    int lo = 0, hi = 2048;
    while (lo < hi) { int mid = (lo + hi) >> 1; if (a[mid] < x) lo = mid + 1; else hi = mid; }
    return lo;
}

// ---------------------------------------------------------------------------
// MCB1 gather, batch-major bf16, phase-partitioned for L2 residency.
// ---------------------------------------------------------------------------
__global__ void __launch_bounds__(256, 8)
mcb1_gather3(const unsigned* __restrict__ atT, const unsigned* __restrict__ vTs,
             const int* __restrict__ pS, float* __restrict__ iq) {
    __shared__ int sp[2048];
    for (int i = threadIdx.x; i < 2048; i += 256) sp[i] = pS[i];
    __syncthreads();

    const int s = blockIdx.y;
    const int w = threadIdx.x >> 5;
    const int q = threadIdx.x & 31;
    const int m0 = blockIdx.x * 64 + w * 8;
    const int m0c = (m0 <= 992) ? m0 : 992;
    const int tb0 = 245 * m0c + s;

    const unsigned* __restrict__ atq = atT + q;
    const unsigned* __restrict__ vtq = vTs + q;

    float accL[8], accH[8];
#pragma unroll
    for (int kk = 0; kk < 8; kk++) { accL[kk] = 0.f; accH[kk] = 0.f; }

    for (int c = 0; c < NP; c++) {
        const int A0 = c * WP;
        const int A1 = A0 + WP;
        int PL = tb0 - A1 + 1; if (PL < 0) PL += D1; if (PL >= D1) PL -= D1;
        int PH = tb0 - A0;     if (PH < 0) PH += D1; if (PH >= D1) PH -= D1;
        int r0a, r1a, r0b, r1b;
        if (PL <= PH) {
            r0a = lbound(sp, PL); r1a = lbound(sp, PH + 1);
            r0b = 0; r1b = 0;
        } else {
            r0a = lbound(sp, PL); r1a = 2048;
            r0b = 0; r1b = lbound(sp, PH + 1);
        }
#pragma unroll 1
        for (int seg = 0; seg < 2; seg++) {
            int rs = seg ? r0b : r0a;
            int re = seg ? r1b : r1a;
            for (int r = rs; r < re; r++) {
                int p = sp[r];
                int qe = (p <= tb0) ? -p : D1 - p;
                unsigned vv = vtq[r * 32];
                float vlo = __uint_as_float(vv << 16);
                float vhi = __uint_as_float(vv & 0xffff0000u);
                const unsigned* row = atq + (size_t)(tb0 + qe) * 32;
#pragma unroll
                for (int kk = 0; kk < 8; kk++) {
                    unsigned u = row[kk * 245 * 32];
                    float alo = __uint_as_float(u << 16);
                    float ahi = __uint_as_float(u & 0xffff0000u);
                    accL[kk] = fmaf(vlo, alo, accL[kk]);
                    accH[kk] = fmaf(vhi, ahi, accH[kk]);
                }
            }
        }
    }

    if (m0 <= 992) {
        float* o0 = iq + ((size_t)(2 * q) * SS + s) * MOUT + m0;
        float* o1 = iq + ((size_t)(2 * q + 1) * SS + s) * MOUT + m0;
#pragma unroll
        for (int kk = 0; kk < 8; kk++) { o0[kk] = accL[kk]; o1[kk] = accH[kk]; }
    }
}

__global__ void ssqrt_l2norm(float* __restrict__ x, int n) {
    __shared__ float red[256];
    __shared__ float inv_s;
    int b = blockIdx.x;
    float* xb = x + (size_t)b * n;
    float ss = 0.f;
    for (int i = threadIdx.x; i < n; i += 256) {
        float v = xb[i];
        float y = (v >= 0.f) ? sqrtf(v) : -sqrtf(-v);
        xb[i] = y;
        ss += y * y;
    }
    red[threadIdx.x] = ss;
    __syncthreads();
    for (int s = 128; s > 0; s >>= 1) {
        if (threadIdx.x < s) red[threadIdx.x] += red[threadIdx.x + s];
        __syncthreads();
    }
    if (threadIdx.x == 0) inv_s = 1.f / fmaxf(sqrtf(red[0]), 1e-12f);
    __syncthreads();
    float inv = inv_s;
    for (int i = threadIdx.x; i < n; i += 256) xb[i] *= inv;
}

__global__ void ifeat_kernel(const float* __restrict__ iatt, const float* __restrict__ img_feat,
                             float* __restrict__ ifeat) {
    int idx = blockIdx.x * blockDim.x + threadIdx.x;
    if (idx >= BB * 4096) return;
    int b = idx >> 12;
    int gf = idx & 4095;
    int g = gf >> 11;
    int f = gf & 2047;
    float acc = 0.f;
    for (int s = 0; s < SS; s++)
        acc += iatt[((size_t)b * 2 + g) * SS + s] * img_feat[((size_t)b * SS + s) * FEAT + f];
    ifeat[idx] = acc;
}

__global__ void mcb2_scatter(const float* __restrict__ ifeat, const int* __restrict__ h2i,
                             const int* __restrict__ s2i, float* __restrict__ atil2) {
    int tid = blockIdx.x * blockDim.x + threadIdx.x;
    if (tid >= BB * 4096) return;
    int i = tid & 4095;
    int b = tid >> 12;
    float v = ifeat[tid] * (float)(2 * s2i[i] - 1);
    int p = h2i[i];
    float* ab = atil2 + (size_t)b * D2;
#pragma unroll
    for (int f = 0; f < 5; f++) {
        int t = p - f;
        if (t < 0) t += D2;
        atomicAdd(&ab[t], v);
    }
}

__global__ void mcb2_gather(const float* __restrict__ atil2, const float* __restrict__ qf,
                            const int* __restrict__ h2q, const int* __restrict__ s2q,
                            float* __restrict__ z) {
    __shared__ float sa[D2];
    __shared__ int sp[2048];
    __shared__ float sv[2048];
    int b = blockIdx.y;
    for (int i = threadIdx.x; i < D2; i += 256) sa[i] = atil2[(size_t)b * D2 + i];
    const float* qb = qf + (size_t)b * 2048;
    for (int j = threadIdx.x; j < 2048; j += 256) {
        sp[j] = h2q[j];
        sv[j] = qb[j] * (float)(2 * s2q[j] - 1);
    }
    __syncthreads();
    int m = blockIdx.x * 256 + threadIdx.x;
    if (m >= MOUT) return;
    int base = 5 * m + D2;
    float acc = 0.f;
#pragma unroll 4
    for (int j = 0; j < 2048; j++) {
        int addr = base - sp[j];
        if (addr >= D2) addr -= D2;
        acc += sv[j] * sa[addr];
    }
    z[(size_t)b * MOUT + m] = acc;
}

__global__ void softmax_rows(const float* __restrict__ logits, float* __restrict__ out, int n) {
    __shared__ float red[256];
    int b = blockIdx.x;
    const float* xr = logits + (size_t)b * n;
    float* orow = out + (size_t)b * n;
    float mx = -1e30f;
    for (int i = threadIdx.x; i < n; i += 256) mx = fmaxf(mx, xr[i]);
    red[threadIdx.x] = mx;
    __syncthreads();
    for (int s = 128; s > 0; s >>= 1) {
        if (threadIdx.x < s) red[threadIdx.x] = fmaxf(red[threadIdx.x], red[threadIdx.x + s]);
        __syncthreads();
    }
    mx = red[0];
    __syncthreads();
    float sum = 0.f;
    for (int i = threadIdx.x; i < n; i += 256) sum += expf(xr[i] - mx);
    red[threadIdx.x] = sum;
    __syncthreads();
    for (int s = 128; s > 0; s >>= 1) {
        if (threadIdx.x < s) red[threadIdx.x] += red[threadIdx.x + s];
        __syncthreads();
    }
    float inv = 1.f / red[0];
    for (int i = threadIdx.x; i < n; i += 256) orow[i] = expf(xr[i] - mx) * inv;
}

extern "C" void kernel_launch(void* const* d_in, const int* in_sizes, int n_in,
                              void* d_out, int out_size, void* d_ws, size_t ws_size,
                              hipStream_t stream) {
    (void)in_sizes; (void)n_in; (void)out_size; (void)ws_size;
    const float* ques = (const float*)d_in[0];
    const float* img  = (const float*)d_in[1];
    const float* W_ih = (const float*)d_in[2];
    const float* W_hh = (const float*)d_in[3];
    const float* b_ih = (const float*)d_in[4];
    const float* b_hh = (const float*)d_in[5];
    const float* Wq1  = (const float*)d_in[6];
    const float* bq1  = (const float*)d_in[7];
    const float* Wq2  = (const float*)d_in[8];
    const float* bq2  = (const float*)d_in[9];
    const float* Wi1  = (const float*)d_in[10];
    const float* bi1  = (const float*)d_in[11];
    const float* Wi2  = (const float*)d_in[12];
    const float* bi2  = (const float*)d_in[13];
    const float* Wp   = (const float*)d_in[14];
    const float* bp   = (const float*)d_in[15];
    const int* h1x = (const int*)d_in[16];
    const int* s1x = (const int*)d_in[17];
    const int* h1q = (const int*)d_in[18];
    const int* s1q = (const int*)d_in[19];
    const int* h2i = (const int*)d_in[20];
    const int* s2i = (const int*)d_in[21];
    const int* h2q = (const int*)d_in[22];
    const int* s2q = (const int*)d_in[23];
    float* out = (float*)d_out;

    // Workspace layout (4 B units). Region A (0..15,680,000) is time-shared:
    // phase1 {xw,hs,hR,bar,qa,qatt,xwT-head} -> afold -> phase2 smalls.
    float* ws = (float*)d_ws;
    float* xw    = ws;                  // 6,815,744
    float* hs    = ws + 6815744;        // 1,703,936
    float* hR    = ws + 8519680;        // 26*65536 = 1,703,936 (h ring)
    unsigned* bar = (unsigned*)(ws + 10223616);  // 1024
    float* qa    = ws + 10224640;       // 851,968
    float* qatt  = ws + 11076608;       // 4,096
    float* xwT   = ws + 11080704;       // 6,815,744 (dead before afold/atT written)
    float* afold = ws;                  // 15,680,000 (written after lstm/qfeat)
    // phase2 smalls (inside region A, alive after transpose)
    float* iq     = ws;                 // 3,136,000
    float* ia     = ws + 3136000;       // 1,605,632
    float* iatt   = ws + 4741632;       // 8,192
    float* ifeat  = ws + 4749824;       // 262,144
    float* atil2  = ws + 5011968;       // 320,000
    float* z      = ws + 5331968;       // 64,000
    float* logits = ws + 5395968;       // 192,000
    // Region B/C
    unsigned* atT  = (unsigned*)(ws + 15680000);  // NROWS*32 = 7,905,536
    float* qf      = ws + 15680000 + 7905536;     // 131,072
    unsigned* vTs  = (unsigned*)(qf + 131072);    // 65,536
    int* pS        = (int*)(vTs + 65536);         // 2,048
    int* permS     = pS + 2048;                   // 2,048

    // ---- sort (independent) ----
    sort_pv<<<1, 1024, 0, stream>>>(h1q, pS, permS);

    // ---- LSTM ----
    hipMemsetAsync(bar, 0, 1024 * 4, stream);
    {   // xW[(b*T+t), g] = ques(b,t,:) . W_ih(g,:) + b_ih + b_hh
        dim3 grid(4096 / 64, (BB * TT + 127) / 128);
        gemm_abt<128, 64, 16, 8, 4, false><<<grid, 256, 0, stream>>>(
            ques, W_ih, b_ih, b_hh, xw, BB * TT, 4 * HH, EE, EE, EE, 4 * HH);
    }
    {
        dim3 grid(TT, 64);
        xwt_transpose<<<grid, 256, 0, stream>>>(xw, xwT);
    }
    lstm_persist3<<<LSTM_BLOCKS, 256, 0, stream>>>(xwT, W_hh, hs, hR, bar);
    // ---- question attention ----
    {
        dim3 grid(512 / 64, (TT * BB + 127) / 128);
        gemm_abt<128, 64, 16, 8, 4, true><<<grid, 256, 0, stream>>>(
            hs, Wq1, bq1, nullptr, qa, TT * BB, 512, HH, HH, HH, 512);
    }
    qa2_kernel<<<(BB * 2 * TT + 255) / 256, 256, 0, stream>>>(qa, Wq2, bq2, qatt);
    softmax_small<<<1, 128, 0, stream>>>(qatt, BB * 2, TT);
    qfeat_kernel<<<(BB * 2048) / 256, 256, 0, stream>>>(qatt, hs, qf);
    // ---- MCB1: fold -> transpose(bf16) -> phased gather ----
    {
        dim3 grid(FOLD_NR, BB);
        sketch_fold<<<grid, 256, 0, stream>>>(img, h1x, s1x, afold);
    }
    {
        int nblk = (NROWS + 63) / 64;
        transpose_bf16<<<nblk, 256, 0, stream>>>(afold, atT);
    }
    vts_build<<<(2048 * 32) / 256, 256, 0, stream>>>(qf, s1q, permS, vTs);
    {
        dim3 grid(16, SS);
        mcb1_gather3<<<grid, 256, 0, stream>>>(atT, vTs, pS, iq);
    }
    ssqrt_l2norm<<<BB, 256, 0, stream>>>(iq, MOUT * SS);
    {
        dim3 grid(512 / 64, (BB * SS + 127) / 128);
        gemm_abt<128, 64, 16, 8, 4, true><<<grid, 256, 0, stream>>>(
            iq, Wi1, bi1, nullptr, ia, BB * SS, 512, MOUT, MOUT, MOUT, 512);
    }
    ia2_kernel<<<(BB * 2 * SS + 255) / 256, 256, 0, stream>>>(ia, Wi2, bi2, iatt);
    softmax_small<<<1, 128, 0, stream>>>(iatt, BB * 2, SS);
    ifeat_kernel<<<(BB * 4096) / 256, 256, 0, stream>>>(iatt, img, ifeat);
    // ---- MCB2 + classifier ----
    hipMemsetAsync(atil2, 0, (size_t)BB * D2 * 4, stream);
    mcb2_scatter<<<(BB * 4096) / 256, 256, 0, stream>>>(ifeat, h2i, s2i, atil2);
    {
        dim3 grid(4, BB);
        mcb2_gather<<<grid, 256, 0, stream>>>(atil2, qf, h2q, s2q, z);
    }
    ssqrt_l2norm<<<BB, 256, 0, stream>>>(z, MOUT);
    {
        dim3 grid((VOCAB + 63) / 64, 4);
        gemm_abt<16, 64, 16, 2, 2, false><<<grid, 256, 0, stream>>>(
            z, Wp, bp, nullptr, logits, BB, VOCAB, MOUT, MOUT, MOUT, VOCAB);
    }
    softmax_rows<<<BB, 256, 0, stream>>>(logits, out, VOCAB);
}

// Round 7
// 4629.569 us; speedup vs baseline: 1.0149x; 1.0149x over previous
//
#include <hip/hip_runtime.h>
#include <math.h>

// Problem constants
static constexpr int BB = 64, TT = 26, EE = 300, HH = 1024;
static constexpr int FEAT = 2048, SS = 49;
static constexpr int D1 = 245000, D2 = 5000;
static constexpr int MOUT = 1000;
static constexpr int VOCAB = 3000;

static constexpr int PAD1T = 2048;               // mod-free pad rows (span <= 245*7+1 = 1716)
static constexpr int NROWS = D1 + PAD1T;         // 247048 rows in transposed sketch
static constexpr int FOLD_R = 16000;
static constexpr int FOLD_NR = 16;
static constexpr int NITEMS = FEAT * SS;         // 100352
static constexpr int NP = 10;                    // gather phases
static constexpr int WP = 24500;                 // phase window (bins); WP*NP = D1

// ---------------------------------------------------------------------------
// Generic fp32 GEMM: C[M,N] = act( A(M,K) * B(N,K)^T + bias1 + bias2 )
// ---------------------------------------------------------------------------
template <int BM, int BN, int BK, int TM, int TN, bool RELU>
__global__ void gemm_abt(const float* __restrict__ A, const float* __restrict__ B,
                         const float* __restrict__ bias1, const float* __restrict__ bias2,
                         float* __restrict__ C,
                         int M, int N, int K, int lda, int ldb, int ldc) {
    constexpr int THREADS = (BM / TM) * (BN / TN);
    __shared__ float As[BK][BM + 1];
    __shared__ float Bs[BK][BN + 1];
    const int tid = threadIdx.x;
    const int tx = tid % (BN / TN);
    const int ty = tid / (BN / TN);
    const int block_m = blockIdx.y * BM;
    const int block_n = blockIdx.x * BN;
    float acc[TM][TN];
#pragma unroll
    for (int i = 0; i < TM; i++)
#pragma unroll
        for (int j = 0; j < TN; j++) acc[i][j] = 0.f;

    for (int k0 = 0; k0 < K; k0 += BK) {
        for (int i = tid; i < BM * BK; i += THREADS) {
            int m = i / BK, kk = i % BK;
            int gm = block_m + m, gk = k0 + kk;
            As[kk][m] = (gm < M && gk < K) ? A[(size_t)gm * lda + gk] : 0.f;
        }
        for (int i = tid; i < BN * BK; i += THREADS) {
            int n = i / BK, kk = i % BK;
            int gn = block_n + n, gk = k0 + kk;
            Bs[kk][n] = (gn < N && gk < K) ? B[(size_t)gn * ldb + gk] : 0.f;
        }
        __syncthreads();
#pragma unroll
        for (int kk = 0; kk < BK; kk++) {
            float a[TM], b[TN];
#pragma unroll
            for (int i = 0; i < TM; i++) a[i] = As[kk][ty * TM + i];
#pragma unroll
            for (int j = 0; j < TN; j++) b[j] = Bs[kk][tx * TN + j];
#pragma unroll
            for (int i = 0; i < TM; i++)
#pragma unroll
                for (int j = 0; j < TN; j++) acc[i][j] += a[i] * b[j];
        }
        __syncthreads();
    }
#pragma unroll
    for (int i = 0; i < TM; i++) {
        int gm = block_m + ty * TM + i;
        if (gm >= M) continue;
#pragma unroll
        for (int j = 0; j < TN; j++) {
            int gn = block_n + tx * TN + j;
            if (gn >= N) continue;
            float v = acc[i][j];
            if (bias1) v += bias1[gn];
            if (bias2) v += bias2[gn];
            if (RELU) v = fmaxf(v, 0.f);
            C[(size_t)gm * ldc + gn] = v;
        }
    }
}

// ---------------------------------------------------------------------------
// xw transpose: xw[(b*T+t), g] -> xwT[(t*4096+g)*64 + b]
// ---------------------------------------------------------------------------
__global__ void xwt_transpose(const float* __restrict__ xw, float* __restrict__ xwT) {
    __shared__ float L[64][65];
    const int t = blockIdx.x;
    const int g0 = blockIdx.y * 64;
    const int tid = threadIdx.x;
    for (int u = 0; u < 16; u++) {
        int idx = u * 256 + tid;
        int b = idx >> 6, g = idx & 63;
        L[g][b] = xw[((size_t)b * TT + t) * 4096 + g0 + g];
    }
    __syncthreads();
    for (int u = 0; u < 16; u++) {
        int idx = u * 256 + tid;
        int g = idx >> 6, b = idx & 63;
        xwT[((size_t)t * 4096 + g0 + g) * 64 + b] = L[g][b];
    }
}

// ---------------------------------------------------------------------------
// LSTM per-step kernel (one launch per step; inter-kernel coherence is the
// runtime's single acquire/release — no grid barrier, no agent atomics).
// 256 blocks x 256 thr. Block owns 4 hidden slots x 4 gates (wave = gate).
// h staged chunk-wise through LDS with register prefetch; c-state in global.
// ---------------------------------------------------------------------------
__global__ void __launch_bounds__(256, 1)
lstm_step(const float* __restrict__ xwT, const float* __restrict__ W_hh,
          const float* __restrict__ hin, float* __restrict__ hout,
          float* __restrict__ cst, float* __restrict__ hs, int step) {
    __shared__ float hl[8192];           // 128 k x 64 b (32 KB)
    __shared__ float part[4][4][64];     // [gate][hh_loc][b]
    const int tid = threadIdx.x;
    const int b = tid & 63;
    const int jw = __builtin_amdgcn_readfirstlane(tid >> 6);   // wave id = gate
    const int hh0 = blockIdx.x * 4;
    const int i_p = tid >> 6;

    if (step > 0) {
        const float* __restrict__ Wbase = W_hh + ((size_t)jw * 1024 + hh0) * 1024;
        float4 pf[8];
        {
            const float4* src = (const float4*)hin;
#pragma unroll
            for (int u = 0; u < 8; u++) pf[u] = src[u * 256 + tid];
        }
        float acc0 = 0.f, acc1 = 0.f, acc2 = 0.f, acc3 = 0.f;
        for (int c = 0; c < 8; c++) {
            __syncthreads();
            {
                float4* dst = (float4*)hl;
#pragma unroll
                for (int u = 0; u < 8; u++) dst[u * 256 + tid] = pf[u];
            }
            __syncthreads();
            if (c < 7) {
                const float4* src = (const float4*)(hin + (c + 1) * 8192);
#pragma unroll
                for (int u = 0; u < 8; u++) pf[u] = src[u * 256 + tid];
            }
            const float* __restrict__ Wr = Wbase + c * 128;
#pragma unroll 4
            for (int kk = 0; kk < 128; kk++) {
                float hv = hl[kk * 64 + b];
                acc0 = fmaf(Wr[kk], hv, acc0);
                acc1 = fmaf(Wr[kk + 1024], hv, acc1);
                acc2 = fmaf(Wr[kk + 2048], hv, acc2);
                acc3 = fmaf(Wr[kk + 3072], hv, acc3);
            }
        }
        part[jw][0][b] = acc0;
        part[jw][1][b] = acc1;
        part[jw][2][b] = acc2;
        part[jw][3][b] = acc3;
        __syncthreads();
    }
    {
        const int row = hh0 + i_p;
        const int idx = row * 64 + b;
        float g4[4];
#pragma unroll
        for (int j = 0; j < 4; j++) {
            float sum = xwT[((size_t)step * 4096 + j * 1024 + row) * 64 + b];
            if (step > 0) sum += part[j][i_p][b];
            g4[j] = sum;
        }
        float si = 1.f / (1.f + expf(-g4[0]));
        float sf = 1.f / (1.f + expf(-g4[1]));
        float tg = tanhf(g4[2]);
        float so = 1.f / (1.f + expf(-g4[3]));
        float cp = (step > 0) ? cst[idx] : 0.f;
        float cn = sf * cp + si * tg;
        cst[idx] = cn;
        float hn = so * tanhf(cn);
        hout[idx] = hn;
        hs[((size_t)step * BB + b) * HH + row] = hn;
    }
}

__global__ void qa2_kernel(const float* __restrict__ qa, const float* __restrict__ Wq2,
                           const float* __restrict__ bq2, float* __restrict__ out) {
    int tid = blockIdx.x * blockDim.x + threadIdx.x;
    if (tid >= BB * 2 * TT) return;
    int t = tid % TT;
    int bg = tid / TT;
    int g = bg & 1;
    const float* arow = qa + ((size_t)t * BB + (bg >> 1)) * 512;
    const float* wrow = Wq2 + g * 512;
    float acc = bq2[g];
    for (int o = 0; o < 512; o++) acc += wrow[o] * arow[o];
    out[tid] = acc;
}

__global__ void ia2_kernel(const float* __restrict__ ia, const float* __restrict__ Wi2,
                           const float* __restrict__ bi2, float* __restrict__ out) {
    int tid = blockIdx.x * blockDim.x + threadIdx.x;
    if (tid >= BB * 2 * SS) return;
    int s = tid % SS;
    int bg = tid / SS;
    int g = bg & 1;
    int b = bg >> 1;
    const float* arow = ia + ((size_t)b * SS + s) * 512;
    const float* wrow = Wi2 + g * 512;
    float acc = bi2[g];
    for (int o = 0; o < 512; o++) acc += wrow[o] * arow[o];
    out[tid] = acc;
}

__global__ void softmax_small(float* __restrict__ x, int rows, int len) {
    int r = blockIdx.x * blockDim.x + threadIdx.x;
    if (r >= rows) return;
    float* xr = x + (size_t)r * len;
    float mx = -1e30f;
    for (int i = 0; i < len; i++) mx = fmaxf(mx, xr[i]);
    float s = 0.f;
    for (int i = 0; i < len; i++) s += expf(xr[i] - mx);
    float inv = 1.f / s;
    for (int i = 0; i < len; i++) xr[i] = expf(xr[i] - mx) * inv;
}

__global__ void qfeat_kernel(const float* __restrict__ qatt, const float* __restrict__ hs,
                             float* __restrict__ qf) {
    int idx = blockIdx.x * blockDim.x + threadIdx.x;
    if (idx >= BB * 2048) return;
    int b = idx >> 11;
    int gh = idx & 2047;
    int g = gh >> 10;
    int hh = gh & 1023;
    float acc = 0.f;
    for (int t = 0; t < TT; t++)
        acc += qatt[((size_t)b * 2 + g) * TT + t] * hs[((size_t)t * BB + b) * HH + hh];
    qf[idx] = acc;
}

// ---------------------------------------------------------------------------
// MCB1 stage A: LDS-privatized scatter + FACTOR fold -> afold[b][t] fp32
// ---------------------------------------------------------------------------
__global__ void sketch_fold(const float* __restrict__ img_feat, const int* __restrict__ h1x,
                            const int* __restrict__ s1x, float* __restrict__ afold) {
    __shared__ float sl[FOLD_R + 196];
    const int b = blockIdx.y;
    const int r0 = blockIdx.x * FOLD_R;
    for (int i = threadIdx.x; i < FOLD_R + 196; i += 256) sl[i] = 0.f;
    __syncthreads();
    for (int i = threadIdx.x; i < NITEMS; i += 256) {
        int h = h1x[i];
        int d = h - r0;
        if (d < 0) d += D1;
        if (d < FOLD_R + 196) {
            int f = i / SS, s = i - f * SS;
            float val = img_feat[((size_t)b * SS + s) * FEAT + f]
                        * (float)(2 * s1x[i] - 1);
            atomicAdd(&sl[d], val);
        }
    }
    __syncthreads();
    float* ab = afold + (size_t)b * D1;
    for (int t = threadIdx.x; t < FOLD_R; t += 256) {
        int g = r0 + t;
        if (g >= D1) break;
        ab[g] = sl[t] + sl[t + 49] + sl[t + 98] + sl[t + 147] + sl[t + 196];
    }
}

__device__ __forceinline__ unsigned short bf16_rne(float x) {
    unsigned u = __float_as_uint(x);
    u += 0x7fffu + ((u >> 16) & 1u);
    return (unsigned short)(u >> 16);
}

// ---------------------------------------------------------------------------
// MCB1 stage B: transpose afold[b][t] -> atT[t][32 x bf16x2], with wrap pad.
// ---------------------------------------------------------------------------
__global__ void transpose_bf16(const float* __restrict__ afold, unsigned* __restrict__ atT) {
    __shared__ float L[64][65];
    const int t0 = blockIdx.x * 64;
    const int tid = threadIdx.x;
    for (int c = 0; c < 16; c++) {
        int idx = c * 256 + tid;          // b*64 + i
        int b = idx >> 6, i = idx & 63;
        int t = t0 + i;
        int src_t = (t < D1) ? t : t - D1;
        L[i][b] = afold[(size_t)b * D1 + src_t];
    }
    __syncthreads();
    for (int c = 0; c < 8; c++) {
        int u = c * 256 + tid;            // t_loc*32 + qq
        int t_loc = u >> 5, qq = u & 31;
        int t = t0 + t_loc;
        if (t >= NROWS) continue;
        unsigned lo = bf16_rne(L[t_loc][2 * qq]);
        unsigned hi = bf16_rne(L[t_loc][2 * qq + 1]);
        atT[(size_t)t * 32 + qq] = lo | (hi << 16);
    }
}

// ---------------------------------------------------------------------------
// Bitonic sort of (h1q, index), 2048 elements, one block of 1024 threads.
// ---------------------------------------------------------------------------
__global__ void sort_pv(const int* __restrict__ h1q, int* __restrict__ pS,
                        int* __restrict__ permS) {
    __shared__ int k[2048], v[2048];
    const int t = threadIdx.x;
    k[t] = h1q[t];          v[t] = t;
    k[t + 1024] = h1q[t + 1024]; v[t + 1024] = t + 1024;
    for (int size = 2; size <= 2048; size <<= 1) {
        for (int stride = size >> 1; stride > 0; stride >>= 1) {
            __syncthreads();
            int pos = 2 * t - (t & (stride - 1));
            bool asc = ((pos & size) == 0);
            int a = k[pos], b = k[pos + stride];
            if ((a > b) == asc) {
                k[pos] = b; k[pos + stride] = a;
                int tmp = v[pos]; v[pos] = v[pos + stride]; v[pos + stride] = tmp;
            }
        }
    }
    __syncthreads();
    pS[t] = k[t]; pS[t + 1024] = k[t + 1024];
    permS[t] = v[t]; permS[t + 1024] = v[t + 1024];
}

// vTs[r][q] = pack_bf16( qf[2q][j]*sgn[j], qf[2q+1][j]*sgn[j] ), j = permS[r]
__global__ void vts_build(const float* __restrict__ qf, const int* __restrict__ s1q,
                          const int* __restrict__ permS, unsigned* __restrict__ vTs) {
    int gid = blockIdx.x * blockDim.x + threadIdx.x;
    if (gid >= 2048 * 32) return;
    int r = gid >> 5, q = gid & 31;
    int j = permS[r];
    float sg = (float)(2 * s1q[j] - 1);
    unsigned lo = bf16_rne(qf[(size_t)(2 * q) * 2048 + j] * sg);
    unsigned hi = bf16_rne(qf[(size_t)(2 * q + 1) * 2048 + j] * sg);
    vTs[gid] = lo | (hi << 16);
}

__device__ __forceinline__ int lbound(const int* a, int x) {
    int lo = 0, hi = 2048;
    while (lo < hi) { int mid = (lo + hi) >> 1; if (a[mid] < x) lo = mid + 1; else hi = mid; }
    return lo;
}

// ---------------------------------------------------------------------------
// MCB1 gather, batch-major bf16, phase-partitioned for L2 residency.
// ---------------------------------------------------------------------------
__global__ void __launch_bounds__(256, 8)
mcb1_gather3(const unsigned* __restrict__ atT, const unsigned* __restrict__ vTs,
             const int* __restrict__ pS, float* __restrict__ iq) {
    __shared__ int sp[2048];
    for (int i = threadIdx.x; i < 2048; i += 256) sp[i] = pS[i];
    __syncthreads();

    const int s = blockIdx.y;
    const int w = threadIdx.x >> 5;
    const int q = threadIdx.x & 31;
    const int m0 = blockIdx.x * 64 + w * 8;
    const int m0c = (m0 <= 992) ? m0 : 992;
    const int tb0 = 245 * m0c + s;

    const unsigned* __restrict__ atq = atT + q;
    const unsigned* __restrict__ vtq = vTs + q;

    float accL[8], accH[8];
#pragma unroll
    for (int kk = 0; kk < 8; kk++) { accL[kk] = 0.f; accH[kk] = 0.f; }

    for (int c = 0; c < NP; c++) {
        const int A0 = c * WP;
        const int A1 = A0 + WP;
        int PL = tb0 - A1 + 1; if (PL < 0) PL += D1; if (PL >= D1) PL -= D1;
        int PH = tb0 - A0;     if (PH < 0) PH += D1; if (PH >= D1) PH -= D1;
        int r0a, r1a, r0b, r1b;
        if (PL <= PH) {
            r0a = lbound(sp, PL); r1a = lbound(sp, PH + 1);
            r0b = 0; r1b = 0;
        } else {
            r0a = lbound(sp, PL); r1a = 2048;
            r0b = 0; r1b = lbound(sp, PH + 1);
        }
#pragma unroll 1
        for (int seg = 0; seg < 2; seg++) {
            int rs = seg ? r0b : r0a;
            int re = seg ? r1b : r1a;
            for (int r = rs; r < re; r++) {
                int p = sp[r];
                int qe = (p <= tb0) ? -p : D1 - p;
                unsigned vv = vtq[r * 32];
                float vlo = __uint_as_float(vv << 16);
                float vhi = __uint_as_float(vv & 0xffff0000u);
                const unsigned* row = atq + (size_t)(tb0 + qe) * 32;
#pragma unroll
                for (int kk = 0; kk < 8; kk++) {
                    unsigned u = row[kk * 245 * 32];
                    float alo = __uint_as_float(u << 16);
                    float ahi = __uint_as_float(u & 0xffff0000u);
                    accL[kk] = fmaf(vlo, alo, accL[kk]);
                    accH[kk] = fmaf(vhi, ahi, accH[kk]);
                }
            }
        }
    }

    if (m0 <= 992) {
        float* o0 = iq + ((size_t)(2 * q) * SS + s) * MOUT + m0;
        float* o1 = iq + ((size_t)(2 * q + 1) * SS + s) * MOUT + m0;
#pragma unroll
        for (int kk = 0; kk < 8; kk++) { o0[kk] = accL[kk]; o1[kk] = accH[kk]; }
    }
}

__global__ void ssqrt_l2norm(float* __restrict__ x, int n) {
    __shared__ float red[256];
    __shared__ float inv_s;
    int b = blockIdx.x;
    float* xb = x + (size_t)b * n;
    float ss = 0.f;
    for (int i = threadIdx.x; i < n; i += 256) {
        float v = xb[i];
        float y = (v >= 0.f) ? sqrtf(v) : -sqrtf(-v);
        xb[i] = y;
        ss += y * y;
    }
    red[threadIdx.x] = ss;
    __syncthreads();
    for (int s = 128; s > 0; s >>= 1) {
        if (threadIdx.x < s) red[threadIdx.x] += red[threadIdx.x + s];
        __syncthreads();
    }
    if (threadIdx.x == 0) inv_s = 1.f / fmaxf(sqrtf(red[0]), 1e-12f);
    __syncthreads();
    float inv = inv_s;
    for (int i = threadIdx.x; i < n; i += 256) xb[i] *= inv;
}

__global__ void ifeat_kernel(const float* __restrict__ iatt, const float* __restrict__ img_feat,
                             float* __restrict__ ifeat) {
    int idx = blockIdx.x * blockDim.x + threadIdx.x;
    if (idx >= BB * 4096) return;
    int b = idx >> 12;
    int gf = idx & 4095;
    int g = gf >> 11;
    int f = gf & 2047;
    float acc = 0.f;
    for (int s = 0; s < SS; s++)
        acc += iatt[((size_t)b * 2 + g) * SS + s] * img_feat[((size_t)b * SS + s) * FEAT + f];
    ifeat[idx] = acc;
}

__global__ void mcb2_scatter(const float* __restrict__ ifeat, const int* __restrict__ h2i,
                             const int* __restrict__ s2i, float* __restrict__ atil2) {
    int tid = blockIdx.x * blockDim.x + threadIdx.x;
    if (tid >= BB * 4096) return;
    int i = tid & 4095;
    int b = tid >> 12;
    float v = ifeat[tid] * (float)(2 * s2i[i] - 1);
    int p = h2i[i];
    float* ab = atil2 + (size_t)b * D2;
#pragma unroll
    for (int f = 0; f < 5; f++) {
        int t = p - f;
        if (t < 0) t += D2;
        atomicAdd(&ab[t], v);
    }
}

__global__ void mcb2_gather(const float* __restrict__ atil2, const float* __restrict__ qf,
                            const int* __restrict__ h2q, const int* __restrict__ s2q,
                            float* __restrict__ z) {
    __shared__ float sa[D2];
    __shared__ int sp[2048];
    __shared__ float sv[2048];
    int b = blockIdx.y;
    for (int i = threadIdx.x; i < D2; i += 256) sa[i] = atil2[(size_t)b * D2 + i];
    const float* qb = qf + (size_t)b * 2048;
    for (int j = threadIdx.x; j < 2048; j += 256) {
        sp[j] = h2q[j];
        sv[j] = qb[j] * (float)(2 * s2q[j] - 1);
    }
    __syncthreads();
    int m = blockIdx.x * 256 + threadIdx.x;
    if (m >= MOUT) return;
    int base = 5 * m + D2;
    float acc = 0.f;
#pragma unroll 4
    for (int j = 0; j < 2048; j++) {
        int addr = base - sp[j];
        if (addr >= D2) addr -= D2;
        acc += sv[j] * sa[addr];
    }
    z[(size_t)b * MOUT + m] = acc;
}

__global__ void softmax_rows(const float* __restrict__ logits, float* __restrict__ out, int n) {
    __shared__ float red[256];
    int b = blockIdx.x;
    const float* xr = logits + (size_t)b * n;
    float* orow = out + (size_t)b * n;
    float mx = -1e30f;
    for (int i = threadIdx.x; i < n; i += 256) mx = fmaxf(mx, xr[i]);
    red[threadIdx.x] = mx;
    __syncthreads();
    for (int s = 128; s > 0; s >>= 1) {
        if (threadIdx.x < s) red[threadIdx.x] = fmaxf(red[threadIdx.x], red[threadIdx.x + s]);
        __syncthreads();
    }
    mx = red[0];
    __syncthreads();
    float sum = 0.f;
    for (int i = threadIdx.x; i < n; i += 256) sum += expf(xr[i] - mx);
    red[threadIdx.x] = sum;
    __syncthreads();
    for (int s = 128; s > 0; s >>= 1) {
        if (threadIdx.x < s) red[threadIdx.x] += red[threadIdx.x + s];
        __syncthreads();
    }
    float inv = 1.f / red[0];
    for (int i = threadIdx.x; i < n; i += 256) orow[i] = expf(xr[i] - mx) * inv;
}

extern "C" void kernel_launch(void* const* d_in, const int* in_sizes, int n_in,
                              void* d_out, int out_size, void* d_ws, size_t ws_size,
                              hipStream_t stream) {
    (void)in_sizes; (void)n_in; (void)out_size; (void)ws_size;
    const float* ques = (const float*)d_in[0];
    const float* img  = (const float*)d_in[1];
    const float* W_ih = (const float*)d_in[2];
    const float* W_hh = (const float*)d_in[3];
    const float* b_ih = (const float*)d_in[4];
    const float* b_hh = (const float*)d_in[5];
    const float* Wq1  = (const float*)d_in[6];
    const float* bq1  = (const float*)d_in[7];
    const float* Wq2  = (const float*)d_in[8];
    const float* bq2  = (const float*)d_in[9];
    const float* Wi1  = (const float*)d_in[10];
    const float* bi1  = (const float*)d_in[11];
    const float* Wi2  = (const float*)d_in[12];
    const float* bi2  = (const float*)d_in[13];
    const float* Wp   = (const float*)d_in[14];
    const float* bp   = (const float*)d_in[15];
    const int* h1x = (const int*)d_in[16];
    const int* s1x = (const int*)d_in[17];
    const int* h1q = (const int*)d_in[18];
    const int* s1q = (const int*)d_in[19];
    const int* h2i = (const int*)d_in[20];
    const int* s2i = (const int*)d_in[21];
    const int* h2q = (const int*)d_in[22];
    const int* s2q = (const int*)d_in[23];
    float* out = (float*)d_out;

    // Workspace layout (4 B units). Region A (0..15,680,000) is time-shared:
    // phase1 {xw,hs,hTa,hTb,cst,qa,qatt,xwT} -> afold -> phase2 smalls.
    float* ws = (float*)d_ws;
    float* xw    = ws;                  // 6,815,744
    float* hs    = ws + 6815744;        // 1,703,936
    float* hTa   = ws + 8519680;        // 65,536
    float* hTb   = ws + 8585216;        // 65,536
    float* cst   = ws + 8650752;        // 65,536
    float* qa    = ws + 10224640;       // 851,968
    float* qatt  = ws + 11076608;       // 4,096
    float* xwT   = ws + 11080704;       // 6,815,744 (dead before afold/atT written)
    float* afold = ws;                  // 15,680,000 (written after lstm/qfeat)
    // phase2 smalls (inside region A, alive after transpose)
    float* iq     = ws;                 // 3,136,000
    float* ia     = ws + 3136000;       // 1,605,632
    float* iatt   = ws + 4741632;       // 8,192
    float* ifeat  = ws + 4749824;       // 262,144
    float* atil2  = ws + 5011968;       // 320,000
    float* z      = ws + 5331968;       // 64,000
    float* logits = ws + 5395968;       // 192,000
    // Region B/C
    unsigned* atT  = (unsigned*)(ws + 15680000);  // NROWS*32 = 7,905,536
    float* qf      = ws + 15680000 + 7905536;     // 131,072
    unsigned* vTs  = (unsigned*)(qf + 131072);    // 65,536
    int* pS        = (int*)(vTs + 65536);         // 2,048
    int* permS     = pS + 2048;                   // 2,048

    // ---- sort (independent) ----
    sort_pv<<<1, 1024, 0, stream>>>(h1q, pS, permS);

    // ---- LSTM ----
    {   // xW[(b*T+t), g] = ques(b,t,:) . W_ih(g,:) + b_ih + b_hh
        dim3 grid(4096 / 64, (BB * TT + 127) / 128);
        gemm_abt<128, 64, 16, 8, 4, false><<<grid, 256, 0, stream>>>(
            ques, W_ih, b_ih, b_hh, xw, BB * TT, 4 * HH, EE, EE, EE, 4 * HH);
    }
    {
        dim3 grid(TT, 64);
        xwt_transpose<<<grid, 256, 0, stream>>>(xw, xwT);
    }
    for (int t = 0; t < TT; t++) {
        float* hout = (t & 1) ? hTb : hTa;
        const float* hin = (t & 1) ? hTa : hTb;   // previous step's hout
        lstm_step<<<256, 256, 0, stream>>>(xwT, W_hh, (t == 0) ? nullptr : hin,
                                           hout, cst, hs, t);
    }
    // ---- question attention ----
    {
        dim3 grid(512 / 64, (TT * BB + 127) / 128);
        gemm_abt<128, 64, 16, 8, 4, true><<<grid, 256, 0, stream>>>(
            hs, Wq1, bq1, nullptr, qa, TT * BB, 512, HH, HH, HH, 512);
    }
    qa2_kernel<<<(BB * 2 * TT + 255) / 256, 256, 0, stream>>>(qa, Wq2, bq2, qatt);
    softmax_small<<<1, 128, 0, stream>>>(qatt, BB * 2, TT);
    qfeat_kernel<<<(BB * 2048) / 256, 256, 0, stream>>>(qatt, hs, qf);
    // ---- MCB1: fold -> transpose(bf16) -> phased gather ----
    {
        dim3 grid(FOLD_NR, BB);
        sketch_fold<<<grid, 256, 0, stream>>>(img, h1x, s1x, afold);
    }
    {
        int nblk = (NROWS + 63) / 64;
        transpose_bf16<<<nblk, 256, 0, stream>>>(afold, atT);
    }
    vts_build<<<(2048 * 32) / 256, 256, 0, stream>>>(qf, s1q, permS, vTs);
    {
        dim3 grid(16, SS);
        mcb1_gather3<<<grid, 256, 0, stream>>>(atT, vTs, pS, iq);
    }
    ssqrt_l2norm<<<BB, 256, 0, stream>>>(iq, MOUT * SS);
    {
        dim3 grid(512 / 64, (BB * SS + 127) / 128);
        gemm_abt<128, 64, 16, 8, 4, true><<<grid, 256, 0, stream>>>(
            iq, Wi1, bi1, nullptr, ia, BB * SS, 512, MOUT, MOUT, MOUT, 512);
    }
    ia2_kernel<<<(BB * 2 * SS + 255) / 256, 256, 0, stream>>>(ia, Wi2, bi2, iatt);
    softmax_small<<<1, 128, 0, stream>>>(iatt, BB * 2, SS);
    ifeat_kernel<<<(BB * 4096) / 256, 256, 0, stream>>>(iatt, img, ifeat);
    // ---- MCB2 + classifier ----
    hipMemsetAsync(atil2, 0, (size_t)BB * D2 * 4, stream);
    mcb2_scatter<<<(BB * 4096) / 256, 256, 0, stream>>>(ifeat, h2i, s2i, atil2);
    {
        dim3 grid(4, BB);
        mcb2_gather<<<grid, 256, 0, stream>>>(atil2, qf, h2q, s2q, z);
    }
    ssqrt_l2norm<<<BB, 256, 0, stream>>>(z, MOUT);
    {
        dim3 grid((VOCAB + 63) / 64, 4);
        gemm_abt<16, 64, 16, 2, 2, false><<<grid, 256, 0, stream>>>(
            z, Wp, bp, nullptr, logits, BB, VOCAB, MOUT, MOUT, MOUT, VOCAB);
    }
    softmax_rows<<<BB, 256, 0, stream>>>(logits, out, VOCAB);
}

// Round 9
// 3614.967 us; speedup vs baseline: 1.2998x; 1.2807x over previous
//
#include <hip/hip_runtime.h>
#include <math.h>

// Problem constants
static constexpr int BB = 64, TT = 26, EE = 300, HH = 1024;
static constexpr int FEAT = 2048, SS = 49;
static constexpr int D1 = 245000, D2 = 5000;
static constexpr int MOUT = 1000;
static constexpr int VOCAB = 3000;

static constexpr int PAD1T = 2048;               // mod-free pad rows (span <= 245*7+1 = 1716)
static constexpr int NROWS = D1 + PAD1T;         // 247048 rows in transposed sketch
static constexpr int FOLD_R = 16000;
static constexpr int FOLD_NR = 16;
static constexpr int BCAP = 8192;                // bucket capacity (mean 6634)
static constexpr int NITEMS = FEAT * SS;         // 100352
static constexpr int NP = 10;                    // gather phases
static constexpr int WP = 24500;                 // phase window (bins); WP*NP = D1

// ---------------------------------------------------------------------------
// Generic fp32 GEMM: C[M,N] = act( A(M,K) * B(N,K)^T + bias1 + bias2 )
// ---------------------------------------------------------------------------
template <int BM, int BN, int BK, int TM, int TN, bool RELU>
__global__ void gemm_abt(const float* __restrict__ A, const float* __restrict__ B,
                         const float* __restrict__ bias1, const float* __restrict__ bias2,
                         float* __restrict__ C,
                         int M, int N, int K, int lda, int ldb, int ldc) {
    constexpr int THREADS = (BM / TM) * (BN / TN);
    __shared__ float As[BK][BM + 1];
    __shared__ float Bs[BK][BN + 1];
    const int tid = threadIdx.x;
    const int tx = tid % (BN / TN);
    const int ty = tid / (BN / TN);
    const int block_m = blockIdx.y * BM;
    const int block_n = blockIdx.x * BN;
    float acc[TM][TN];
#pragma unroll
    for (int i = 0; i < TM; i++)
#pragma unroll
        for (int j = 0; j < TN; j++) acc[i][j] = 0.f;

    for (int k0 = 0; k0 < K; k0 += BK) {
        for (int i = tid; i < BM * BK; i += THREADS) {
            int m = i / BK, kk = i % BK;
            int gm = block_m + m, gk = k0 + kk;
            As[kk][m] = (gm < M && gk < K) ? A[(size_t)gm * lda + gk] : 0.f;
        }
        for (int i = tid; i < BN * BK; i += THREADS) {
            int n = i / BK, kk = i % BK;
            int gn = block_n + n, gk = k0 + kk;
            Bs[kk][n] = (gn < N && gk < K) ? B[(size_t)gn * ldb + gk] : 0.f;
        }
        __syncthreads();
#pragma unroll
        for (int kk = 0; kk < BK; kk++) {
            float a[TM], b[TN];
#pragma unroll
            for (int i = 0; i < TM; i++) a[i] = As[kk][ty * TM + i];
#pragma unroll
            for (int j = 0; j < TN; j++) b[j] = Bs[kk][tx * TN + j];
#pragma unroll
            for (int i = 0; i < TM; i++)
#pragma unroll
                for (int j = 0; j < TN; j++) acc[i][j] += a[i] * b[j];
        }
        __syncthreads();
    }
#pragma unroll
    for (int i = 0; i < TM; i++) {
        int gm = block_m + ty * TM + i;
        if (gm >= M) continue;
#pragma unroll
        for (int j = 0; j < TN; j++) {
            int gn = block_n + tx * TN + j;
            if (gn >= N) continue;
            float v = acc[i][j];
            if (bias1) v += bias1[gn];
            if (bias2) v += bias2[gn];
            if (RELU) v = fmaxf(v, 0.f);
            C[(size_t)gm * ldc + gn] = v;
        }
    }
}

// ---------------------------------------------------------------------------
// xw transpose: xw[(b*T+t), g] -> xwT[(t*4096+g)*64 + b]
// ---------------------------------------------------------------------------
__global__ void xwt_transpose(const float* __restrict__ xw, float* __restrict__ xwT) {
    __shared__ float L[64][65];
    const int t = blockIdx.x;
    const int g0 = blockIdx.y * 64;
    const int tid = threadIdx.x;
    for (int u = 0; u < 16; u++) {
        int idx = u * 256 + tid;
        int b = idx >> 6, g = idx & 63;
        L[g][b] = xw[((size_t)b * TT + t) * 4096 + g0 + g];
    }
    __syncthreads();
    for (int u = 0; u < 16; u++) {
        int idx = u * 256 + tid;
        int g = idx >> 6, b = idx & 63;
        xwT[((size_t)t * 4096 + g0 + g) * 64 + b] = L[g][b];
    }
}

// ---------------------------------------------------------------------------
// LSTM per-step kernel v2. 512 blocks x 256 thr (2 blocks/CU, 2 waves/SIMD).
// Block owns 2 hidden slots x 4 gates (wave = gate). h staged through LDS in
// 16 KB chunks, double-buffered (one sync per chunk) with register prefetch.
// ---------------------------------------------------------------------------
__global__ void __launch_bounds__(256, 2)
lstm_step2(const float* __restrict__ xwT, const float* __restrict__ W_hh,
           const float* __restrict__ hin, float* __restrict__ hout,
           float* __restrict__ cst, float* __restrict__ hs, int step) {
    __shared__ float hl[2][4096];        // two 16 KB buffers: 64 k x 64 b
    __shared__ float part[4][2][64];     // [gate][hh_loc][b]
    const int tid = threadIdx.x;
    const int b = tid & 63;
    const int jw = __builtin_amdgcn_readfirstlane(tid >> 6);   // wave id = gate
    const int hh0 = blockIdx.x * 2;

    if (step > 0) {
        const float* __restrict__ Wbase = W_hh + ((size_t)jw * 1024 + hh0) * 1024;
        const float4* __restrict__ src = (const float4*)hin;
        float4 pf0 = src[tid];
        float4 pf1 = src[256 + tid];
        float4 pf2 = src[512 + tid];
        float4 pf3 = src[768 + tid];
        float acc0 = 0.f, acc1 = 0.f;
        for (int c = 0; c < 16; c++) {
            float4* dst = (float4*)hl[c & 1];
            dst[tid] = pf0; dst[256 + tid] = pf1;
            dst[512 + tid] = pf2; dst[768 + tid] = pf3;
            __syncthreads();                       // hl[c&1] ready; also protects
                                                   // next iter's write of other buf
            if (c < 15) {
                const float4* s2 = src + (c + 1) * 1024;
                pf0 = s2[tid]; pf1 = s2[256 + tid];
                pf2 = s2[512 + tid]; pf3 = s2[768 + tid];
            }
            const float* __restrict__ Wr = Wbase + c * 64;
            const float* __restrict__ hb = hl[c & 1];
#pragma unroll 8
            for (int kk = 0; kk < 64; kk++) {
                float hv = hb[kk * 64 + b];
                acc0 = fmaf(Wr[kk], hv, acc0);
                acc1 = fmaf(Wr[kk + 1024], hv, acc1);
            }
        }
        part[jw][0][b] = acc0;
        part[jw][1][b] = acc1;
        __syncthreads();
    }
    if (tid < 128) {
        const int i_p = tid >> 6;
        const int row = hh0 + i_p;
        const int idx = row * 64 + b;
        float g4[4];
#pragma unroll
        for (int j = 0; j < 4; j++) {
            float sum = xwT[((size_t)step * 4096 + j * 1024 + row) * 64 + b];
            if (step > 0) sum += part[j][i_p][b];
            g4[j] = sum;
        }
        float si = 1.f / (1.f + expf(-g4[0]));
        float sf = 1.f / (1.f + expf(-g4[1]));
        float tg = tanhf(g4[2]);
        float so = 1.f / (1.f + expf(-g4[3]));
        float cp = (step > 0) ? cst[idx] : 0.f;
        float cn = sf * cp + si * tg;
        cst[idx] = cn;
        float hn = so * tanhf(cn);
        hout[idx] = hn;
        hs[((size_t)step * BB + b) * HH + row] = hn;
    }
}

__global__ void qa2_kernel(const float* __restrict__ qa, const float* __restrict__ Wq2,
                           const float* __restrict__ bq2, float* __restrict__ out) {
    int tid = blockIdx.x * blockDim.x + threadIdx.x;
    if (tid >= BB * 2 * TT) return;
    int t = tid % TT;
    int bg = tid / TT;
    int g = bg & 1;
    const float* arow = qa + ((size_t)t * BB + (bg >> 1)) * 512;
    const float* wrow = Wq2 + g * 512;
    float acc = bq2[g];
    for (int o = 0; o < 512; o++) acc += wrow[o] * arow[o];
    out[tid] = acc;
}

__global__ void ia2_kernel(const float* __restrict__ ia, const float* __restrict__ Wi2,
                           const float* __restrict__ bi2, float* __restrict__ out) {
    int tid = blockIdx.x * blockDim.x + threadIdx.x;
    if (tid >= BB * 2 * SS) return;
    int s = tid % SS;
    int bg = tid / SS;
    int g = bg & 1;
    int b = bg >> 1;
    const float* arow = ia + ((size_t)b * SS + s) * 512;
    const float* wrow = Wi2 + g * 512;
    float acc = bi2[g];
    for (int o = 0; o < 512; o++) acc += wrow[o] * arow[o];
    out[tid] = acc;
}

__global__ void softmax_small(float* __restrict__ x, int rows, int len) {
    int r = blockIdx.x * blockDim.x + threadIdx.x;
    if (r >= rows) return;
    float* xr = x + (size_t)r * len;
    float mx = -1e30f;
    for (int i = 0; i < len; i++) mx = fmaxf(mx, xr[i]);
    float s = 0.f;
    for (int i = 0; i < len; i++) s += expf(xr[i] - mx);
    float inv = 1.f / s;
    for (int i = 0; i < len; i++) xr[i] = expf(xr[i] - mx) * inv;
}

__global__ void qfeat_kernel(const float* __restrict__ qatt, const float* __restrict__ hs,
                             float* __restrict__ qf) {
    int idx = blockIdx.x * blockDim.x + threadIdx.x;
    if (idx >= BB * 2048) return;
    int b = idx >> 11;
    int gh = idx & 2047;
    int g = gh >> 10;
    int hh = gh & 1023;
    float acc = 0.f;
    for (int t = 0; t < TT; t++)
        acc += qatt[((size_t)b * 2 + g) * TT + t] * hs[((size_t)t * BB + b) * HH + hh];
    qf[idx] = acc;
}

// ---------------------------------------------------------------------------
// Bucket build: scatter items into 16 overlapping bin-window buckets (once).
// Item i: h = h1x[i]; payload = img offset (s*FEAT+f) | sign<<31.
// ---------------------------------------------------------------------------
__global__ void bucket_build(const int* __restrict__ h1x, const int* __restrict__ s1x,
                             int* __restrict__ bcnt, int* __restrict__ bkh,
                             int* __restrict__ bkp) {
    int i = blockIdx.x * 256 + threadIdx.x;
    if (i >= NITEMS) return;
    int h = h1x[i];
    int f = i / SS, s = i - f * SS;
    int pay = (s * FEAT + f) | (s1x[i] << 31);
#pragma unroll
    for (int r = 0; r < FOLD_NR; r++) {
        int dd = h - r * FOLD_R;
        if (dd < 0) dd += D1;
        if (dd < FOLD_R + 196) {
            int pos = atomicAdd(&bcnt[r], 1);
            if (pos < BCAP) {
                bkh[r * BCAP + pos] = h;
                bkp[r * BCAP + pos] = pay;
            }
        }
    }
}

// ---------------------------------------------------------------------------
// MCB1 stage A v2: block (r, b) scans only bucket r (~6.6K items, not 100K),
// LDS-privatized scatter + FACTOR fold -> afold[b][t] fp32.
// ---------------------------------------------------------------------------
__global__ void sketch_fold2(const float* __restrict__ img_feat, const int* __restrict__ bcnt,
                             const int* __restrict__ bkh, const int* __restrict__ bkp,
                             float* __restrict__ afold) {
    __shared__ float sl[FOLD_R + 196];
    const int r = blockIdx.x;
    const int b = blockIdx.y;
    const int r0 = r * FOLD_R;
    for (int i = threadIdx.x; i < FOLD_R + 196; i += 256) sl[i] = 0.f;
    __syncthreads();
    const int n = min(bcnt[r], BCAP);
    const float* __restrict__ ib = img_feat + (size_t)b * NITEMS;
    for (int j = threadIdx.x; j < n; j += 256) {
        int h = bkh[r * BCAP + j];
        int pay = bkp[r * BCAP + j];
        int d = h - r0;
        if (d < 0) d += D1;
        float v = ib[pay & 0x7FFFFFFF];
        float val = ((unsigned)pay >> 31) ? v : -v;   // s1x=1 -> +1, 0 -> -1
        atomicAdd(&sl[d], val);
    }
    __syncthreads();
    float* ab = afold + (size_t)b * D1;
    for (int t = threadIdx.x; t < FOLD_R; t += 256) {
        int g = r0 + t;
        if (g >= D1) break;
        ab[g] = sl[t] + sl[t + 49] + sl[t + 98] + sl[t + 147] + sl[t + 196];
    }
}

__device__ __forceinline__ unsigned short bf16_rne(float x) {
    unsigned u = __float_as_uint(x);
    u += 0x7fffu + ((u >> 16) & 1u);
    return (unsigned short)(u >> 16);
}

// ---------------------------------------------------------------------------
// MCB1 stage B: transpose afold[b][t] -> atT[t][32 x bf16x2], with wrap pad.
// ---------------------------------------------------------------------------
__global__ void transpose_bf16(const float* __restrict__ afold, unsigned* __restrict__ atT) {
    __shared__ float L[64][65];
    const int t0 = blockIdx.x * 64;
    const int tid = threadIdx.x;
    for (int c = 0; c < 16; c++) {
        int idx = c * 256 + tid;          // b*64 + i
        int b = idx >> 6, i = idx & 63;
        int t = t0 + i;
        int src_t = (t < D1) ? t : t - D1;
        L[i][b] = afold[(size_t)b * D1 + src_t];
    }
    __syncthreads();
    for (int c = 0; c < 8; c++) {
        int u = c * 256 + tid;            // t_loc*32 + qq
        int t_loc = u >> 5, qq = u & 31;
        int t = t0 + t_loc;
        if (t >= NROWS) continue;
        unsigned lo = bf16_rne(L[t_loc][2 * qq]);
        unsigned hi = bf16_rne(L[t_loc][2 * qq + 1]);
        atT[(size_t)t * 32 + qq] = lo | (hi << 16);
    }
}

// ---------------------------------------------------------------------------
// Bitonic sort of (h1q, index), 2048 elements, one block of 1024 threads.
// ---------------------------------------------------------------------------
__global__ void sort_pv(const int* __restrict__ h1q, int* __restrict__ pS,
                        int* __restrict__ permS) {
    __shared__ int k[2048], v[2048];
    const int t = threadIdx.x;
    k[t] = h1q[t];          v[t] = t;
    k[t + 1024] = h1q[t + 1024]; v[t + 1024] = t + 1024;
    for (int size = 2; size <= 2048; size <<= 1) {
        for (int stride = size >> 1; stride > 0; stride >>= 1) {
            __syncthreads();
            int pos = 2 * t - (t & (stride - 1));
            bool asc = ((pos & size) == 0);
            int a = k[pos], b = k[pos + stride];
            if ((a > b) == asc) {
                k[pos] = b; k[pos + stride] = a;
                int tmp = v[pos]; v[pos] = v[pos + stride]; v[pos + stride] = tmp;
            }
        }
    }
    __syncthreads();
    pS[t] = k[t]; pS[t + 1024] = k[t + 1024];
    permS[t] = v[t]; permS[t + 1024] = v[t + 1024];
}

// vTs[r][q] = pack_bf16( qf[2q][j]*sgn[j], qf[2q+1][j]*sgn[j] ), j = permS[r]
__global__ void vts_build(const float* __restrict__ qf, const int* __restrict__ s1q,
                          const int* __restrict__ permS, unsigned* __restrict__ vTs) {
    int gid = blockIdx.x * blockDim.x + threadIdx.x;
    if (gid >= 2048 * 32) return;
    int r = gid >> 5, q = gid & 31;
    int j = permS[r];
    float sg = (float)(2 * s1q[j] - 1);
    unsigned lo = bf16_rne(qf[(size_t)(2 * q) * 2048 + j] * sg);
    unsigned hi = bf16_rne(qf[(size_t)(2 * q + 1) * 2048 + j] * sg);
    vTs[gid] = lo | (hi << 16);
}

__device__ __forceinline__ int lbound(const int* a, int x) {
    int lo = 0, hi = 2048;
    while (lo < hi) { int mid = (lo + hi) >> 1; if (a[mid] < x) lo = mid + 1; else hi = mid; }
    return lo;
}

// ---------------------------------------------------------------------------
// MCB1 gather, batch-major bf16, phase-partitioned for L2 residency.
// ---------------------------------------------------------------------------
__global__ void __launch_bounds__(256, 8)
mcb1_gather3(const unsigned* __restrict__ atT, const unsigned* __restrict__ vTs,
             const int* __restrict__ pS, float* __restrict__ iq) {
    __shared__ int sp[2048];
    for (int i = threadIdx.x; i < 2048; i += 256) sp[i] = pS[i];
    __syncthreads();

    const int s = blockIdx.y;
    const int w = threadIdx.x >> 5;
    const int q = threadIdx.x & 31;
    const int m0 = blockIdx.x * 64 + w * 8;
    const int m0c = (m0 <= 992) ? m0 : 992;
    const int tb0 = 245 * m0c + s;

    const unsigned* __restrict__ atq = atT + q;
    const unsigned* __restrict__ vtq = vTs + q;

    float accL[8], accH[8];
#pragma unroll
    for (int kk = 0; kk < 8; kk++) { accL[kk] = 0.f; accH[kk] = 0.f; }

    for (int c = 0; c < NP; c++) {
        const int A0 = c * WP;
        const int A1 = A0 + WP;
        int PL = tb0 - A1 + 1; if (PL < 0) PL += D1; if (PL >= D1) PL -= D1;
        int PH = tb0 - A0;     if (PH < 0) PH += D1; if (PH >= D1) PH -= D1;
        int r0a, r1a, r0b, r1b;
        if (PL <= PH) {
            r0a = lbound(sp, PL); r1a = lbound(sp, PH + 1);
            r0b = 0; r1b = 0;
        } else {
            r0a = lbound(sp, PL); r1a = 2048;
            r0b = 0; r1b = lbound(sp, PH + 1);
        }
#pragma unroll 1
        for (int seg = 0; seg < 2; seg++) {
            int rs = seg ? r0b : r0a;
            int re = seg ? r1b : r1a;
            for (int r = rs; r < re; r++) {
                int p = sp[r];
                int qe = (p <= tb0) ? -p : D1 - p;
                unsigned vv = vtq[r * 32];
                float vlo = __uint_as_float(vv << 16);
                float vhi = __uint_as_float(vv & 0xffff0000u);
                const unsigned* row = atq + (size_t)(tb0 + qe) * 32;
#pragma unroll
                for (int kk = 0; kk < 8; kk++) {
                    unsigned u = row[kk * 245 * 32];
                    float alo = __uint_as_float(u << 16);
                    float ahi = __uint_as_float(u & 0xffff0000u);
                    accL[kk] = fmaf(vlo, alo, accL[kk]);
                    accH[kk] = fmaf(vhi, ahi, accH[kk]);
                }
            }
        }
    }

    if (m0 <= 992) {
        float* o0 = iq + ((size_t)(2 * q) * SS + s) * MOUT + m0;
        float* o1 = iq + ((size_t)(2 * q + 1) * SS + s) * MOUT + m0;
#pragma unroll
        for (int kk = 0; kk < 8; kk++) { o0[kk] = accL[kk]; o1[kk] = accH[kk]; }
    }
}

__global__ void ssqrt_l2norm(float* __restrict__ x, int n) {
    __shared__ float red[256];
    __shared__ float inv_s;
    int b = blockIdx.x;
    float* xb = x + (size_t)b * n;
    float ss = 0.f;
    for (int i = threadIdx.x; i < n; i += 256) {
        float v = xb[i];
        float y = (v >= 0.f) ? sqrtf(v) : -sqrtf(-v);
        xb[i] = y;
        ss += y * y;
    }
    red[threadIdx.x] = ss;
    __syncthreads();
    for (int s = 128; s > 0; s >>= 1) {
        if (threadIdx.x < s) red[threadIdx.x] += red[threadIdx.x + s];
        __syncthreads();
    }
    if (threadIdx.x == 0) inv_s = 1.f / fmaxf(sqrtf(red[0]), 1e-12f);
    __syncthreads();
    float inv = inv_s;
    for (int i = threadIdx.x; i < n; i += 256) xb[i] *= inv;
}

__global__ void ifeat_kernel(const float* __restrict__ iatt, const float* __restrict__ img_feat,
                             float* __restrict__ ifeat) {
    int idx = blockIdx.x * blockDim.x + threadIdx.x;
    if (idx >= BB * 4096) return;
    int b = idx >> 12;
    int gf = idx & 4095;
    int g = gf >> 11;
    int f = gf & 2047;
    float acc = 0.f;
    for (int s = 0; s < SS; s++)
        acc += iatt[((size_t)b * 2 + g) * SS + s] * img_feat[((size_t)b * SS + s) * FEAT + f];
    ifeat[idx] = acc;
}

__global__ void mcb2_scatter(const float* __restrict__ ifeat, const int* __restrict__ h2i,
                             const int* __restrict__ s2i, float* __restrict__ atil2) {
    int tid = blockIdx.x * blockDim.x + threadIdx.x;
    if (tid >= BB * 4096) return;
    int i = tid & 4095;
    int b = tid >> 12;
    float v = ifeat[tid] * (float)(2 * s2i[i] - 1);
    int p = h2i[i];
    float* ab = atil2 + (size_t)b * D2;
#pragma unroll
    for (int f = 0; f < 5; f++) {
        int t = p - f;
        if (t < 0) t += D2;
        atomicAdd(&ab[t], v);
    }
}

__global__ void mcb2_gather(const float* __restrict__ atil2, const float* __restrict__ qf,
                            const int* __restrict__ h2q, const int* __restrict__ s2q,
                            float* __restrict__ z) {
    __shared__ float sa[D2];
    __shared__ int sp[2048];
    __shared__ float sv[2048];
    int b = blockIdx.y;
    for (int i = threadIdx.x; i < D2; i += 256) sa[i] = atil2[(size_t)b * D2 + i];
    const float* qb = qf + (size_t)b * 2048;
    for (int j = threadIdx.x; j < 2048; j += 256) {
        sp[j] = h2q[j];
        sv[j] = qb[j] * (float)(2 * s2q[j] - 1);
    }
    __syncthreads();
    int m = blockIdx.x * 256 + threadIdx.x;
    if (m >= MOUT) return;
    int base = 5 * m + D2;
    float acc = 0.f;
#pragma unroll 4
    for (int j = 0; j < 2048; j++) {
        int addr = base - sp[j];
        if (addr >= D2) addr -= D2;
        acc += sv[j] * sa[addr];
    }
    z[(size_t)b * MOUT + m] = acc;
}

__global__ void softmax_rows(const float* __restrict__ logits, float* __restrict__ out, int n) {
    __shared__ float red[256];
    int b = blockIdx.x;
    const float* xr = logits + (size_t)b * n;
    float* orow = out + (size_t)b * n;
    float mx = -1e30f;
    for (int i = threadIdx.x; i < n; i += 256) mx = fmaxf(mx, xr[i]);
    red[threadIdx.x] = mx;
    __syncthreads();
    for (int s = 128; s > 0; s >>= 1) {
        if (threadIdx.x < s) red[threadIdx.x] = fmaxf(red[threadIdx.x], red[threadIdx.x + s]);
        __syncthreads();
    }
    mx = red[0];
    __syncthreads();
    float sum = 0.f;
    for (int i = threadIdx.x; i < n; i += 256) sum += expf(xr[i] - mx);
    red[threadIdx.x] = sum;
    __syncthreads();
    for (int s = 128; s > 0; s >>= 1) {
        if (threadIdx.x < s) red[threadIdx.x] += red[threadIdx.x + s];
        __syncthreads();
    }
    float inv = 1.f / red[0];
    for (int i = threadIdx.x; i < n; i += 256) orow[i] = expf(xr[i] - mx) * inv;
}

extern "C" void kernel_launch(void* const* d_in, const int* in_sizes, int n_in,
                              void* d_out, int out_size, void* d_ws, size_t ws_size,
                              hipStream_t stream) {
    (void)in_sizes; (void)n_in; (void)out_size; (void)ws_size;
    const float* ques = (const float*)d_in[0];
    const float* img  = (const float*)d_in[1];
    const float* W_ih = (const float*)d_in[2];
    const float* W_hh = (const float*)d_in[3];
    const float* b_ih = (const float*)d_in[4];
    const float* b_hh = (const float*)d_in[5];
    const float* Wq1  = (const float*)d_in[6];
    const float* bq1  = (const float*)d_in[7];
    const float* Wq2  = (const float*)d_in[8];
    const float* bq2  = (const float*)d_in[9];
    const float* Wi1  = (const float*)d_in[10];
    const float* bi1  = (const float*)d_in[11];
    const float* Wi2  = (const float*)d_in[12];
    const float* bi2  = (const float*)d_in[13];
    const float* Wp   = (const float*)d_in[14];
    const float* bpc  = (const float*)d_in[15];   // classifier bias (renamed)
    const int* h1x = (const int*)d_in[16];
    const int* s1x = (const int*)d_in[17];
    const int* h1q = (const int*)d_in[18];
    const int* s1q = (const int*)d_in[19];
    const int* h2i = (const int*)d_in[20];
    const int* s2i = (const int*)d_in[21];
    const int* h2q = (const int*)d_in[22];
    const int* s2q = (const int*)d_in[23];
    float* out = (float*)d_out;

    // Workspace layout (4 B units). Region A (0..15,680,000) time-shared:
    // phase1 {xw,hs,hTa,hTb,cst,qa,qatt,xwT} -> afold -> phase2 smalls.
    float* ws = (float*)d_ws;
    float* xw    = ws;                  // 6,815,744
    float* hs    = ws + 6815744;        // 1,703,936
    float* hTa   = ws + 8519680;        // 65,536
    float* hTb   = ws + 8585216;        // 65,536
    float* cst   = ws + 8650752;        // 65,536
    float* qa    = ws + 10224640;       // 851,968
    float* qatt  = ws + 11076608;       // 4,096
    float* xwT   = ws + 11080704;       // 6,815,744 (dead before afold written)
    float* afold = ws;                  // 15,680,000 (written after lstm/qfeat)
    // phase2 smalls (inside region A, alive after transpose)
    float* iq     = ws;                 // 3,136,000
    float* ia     = ws + 3136000;       // 1,605,632
    float* iatt   = ws + 4741632;       // 8,192
    float* ifeat  = ws + 4749824;       // 262,144
    float* atil2  = ws + 5011968;       // 320,000
    float* z      = ws + 5331968;       // 64,000
    float* logits = ws + 5395968;       // 192,000
    // Region B/C (persistent across phases)
    unsigned* atT  = (unsigned*)(ws + 15680000);  // NROWS*32 = 7,905,536
    float* qf      = ws + 15680000 + 7905536;     // 131,072
    unsigned* vTs  = (unsigned*)(qf + 131072);    // 65,536
    int* pS        = (int*)(vTs + 65536);         // 2,048
    int* permS     = pS + 2048;                   // 2,048
    int* bcnt      = permS + 2048;                // 64 (16 used)
    int* bkh       = bcnt + 64;                   // 16*8192 = 131,072
    int* bkp       = bkh + FOLD_NR * BCAP;        // 131,072  (end ~96.2 MB)

    // ---- independent preprocessing ----
    sort_pv<<<1, 1024, 0, stream>>>(h1q, pS, permS);
    (void)hipMemsetAsync(bcnt, 0, 64 * 4, stream);
    bucket_build<<<(NITEMS + 255) / 256, 256, 0, stream>>>(h1x, s1x, bcnt, bkh, bkp);

    // ---- LSTM ----
    {   // xW[(b*T+t), g] = ques(b,t,:) . W_ih(g,:) + b_ih + b_hh
        dim3 grid(4096 / 64, (BB * TT + 127) / 128);
        gemm_abt<128, 64, 16, 8, 4, false><<<grid, 256, 0, stream>>>(
            ques, W_ih, b_ih, b_hh, xw, BB * TT, 4 * HH, EE, EE, EE, 4 * HH);
    }
    {
        dim3 grid(TT, 64);
        xwt_transpose<<<grid, 256, 0, stream>>>(xw, xwT);
    }
    for (int t = 0; t < TT; t++) {
        float* hout = (t & 1) ? hTb : hTa;
        const float* hin = (t & 1) ? hTa : hTb;   // previous step's hout
        lstm_step2<<<512, 256, 0, stream>>>(xwT, W_hh, (t == 0) ? nullptr : hin,
                                            hout, cst, hs, t);
    }
    // ---- question attention ----
    {
        dim3 grid(512 / 64, (TT * BB + 127) / 128);
        gemm_abt<128, 64, 16, 8, 4, true><<<grid, 256, 0, stream>>>(
            hs, Wq1, bq1, nullptr, qa, TT * BB, 512, HH, HH, HH, 512);
    }
    qa2_kernel<<<(BB * 2 * TT + 255) / 256, 256, 0, stream>>>(qa, Wq2, bq2, qatt);
    softmax_small<<<1, 128, 0, stream>>>(qatt, BB * 2, TT);
    qfeat_kernel<<<(BB * 2048) / 256, 256, 0, stream>>>(qatt, hs, qf);
    // ---- MCB1: bucketed fold -> transpose(bf16) -> phased gather ----
    {
        dim3 grid(FOLD_NR, BB);
        sketch_fold2<<<grid, 256, 0, stream>>>(img, bcnt, bkh, bkp, afold);
    }
    {
        int nblk = (NROWS + 63) / 64;
        transpose_bf16<<<nblk, 256, 0, stream>>>(afold, atT);
    }
    vts_build<<<(2048 * 32) / 256, 256, 0, stream>>>(qf, s1q, permS, vTs);
    {
        dim3 grid(16, SS);
        mcb1_gather3<<<grid, 256, 0, stream>>>(atT, vTs, pS, iq);
    }
    ssqrt_l2norm<<<BB, 256, 0, stream>>>(iq, MOUT * SS);
    {
        dim3 grid(512 / 64, (BB * SS + 127) / 128);
        gemm_abt<128, 64, 16, 8, 4, true><<<grid, 256, 0, stream>>>(
            iq, Wi1, bi1, nullptr, ia, BB * SS, 512, MOUT, MOUT, MOUT, 512);
    }
    ia2_kernel<<<(BB * 2 * SS + 255) / 256, 256, 0, stream>>>(ia, Wi2, bi2, iatt);
    softmax_small<<<1, 128, 0, stream>>>(iatt, BB * 2, SS);
    ifeat_kernel<<<(BB * 4096) / 256, 256, 0, stream>>>(iatt, img, ifeat);
    // ---- MCB2 + classifier ----
    (void)hipMemsetAsync(atil2, 0, (size_t)BB * D2 * 4, stream);
    mcb2_scatter<<<(BB * 4096) / 256, 256, 0, stream>>>(ifeat, h2i, s2i, atil2);
    {
        dim3 grid(4, BB);
        mcb2_gather<<<grid, 256, 0, stream>>>(atil2, qf, h2q, s2q, z);
    }
    ssqrt_l2norm<<<BB, 256, 0, stream>>>(z, MOUT);
    {
        dim3 grid((VOCAB + 63) / 64, 4);
        gemm_abt<16, 64, 16, 2, 2, false><<<grid, 256, 0, stream>>>(
            z, Wp, bpc, nullptr, logits, BB, VOCAB, MOUT, MOUT, MOUT, VOCAB);
    }
    softmax_rows<<<BB, 256, 0, stream>>>(logits, out, VOCAB);
}

// Round 10
// 3607.273 us; speedup vs baseline: 1.3026x; 1.0021x over previous
//
#include <hip/hip_runtime.h>
#include <hip/hip_fp16.h>
#include <math.h>

// Problem constants
static constexpr int BB = 64, TT = 26, EE = 300, HH = 1024;
static constexpr int FEAT = 2048, SS = 49;
static constexpr int D1 = 245000, D2 = 5000;
static constexpr int MOUT = 1000;
static constexpr int VOCAB = 3000;

static constexpr int PAD1T = 2048;               // mod-free pad rows (span <= 245*7+1 = 1716)
static constexpr int NROWS = D1 + PAD1T;         // 247048 rows in transposed sketch
static constexpr int FOLD_R = 16000;
static constexpr int FOLD_NR = 16;
static constexpr int BCAP = 8192;                // bucket capacity (mean 6634)
static constexpr int NITEMS = FEAT * SS;         // 100352
static constexpr int NP = 10;                    // gather phases
static constexpr int WP = 24500;                 // phase window (bins); WP*NP = D1

// ---------------------------------------------------------------------------
// Generic fp32 GEMM: C[M,N] = act( A(M,K) * B(N,K)^T + bias1 + bias2 )
// ---------------------------------------------------------------------------
template <int BM, int BN, int BK, int TM, int TN, bool RELU>
__global__ void gemm_abt(const float* __restrict__ A, const float* __restrict__ B,
                         const float* __restrict__ bias1, const float* __restrict__ bias2,
                         float* __restrict__ C,
                         int M, int N, int K, int lda, int ldb, int ldc) {
    constexpr int THREADS = (BM / TM) * (BN / TN);
    __shared__ float As[BK][BM + 1];
    __shared__ float Bs[BK][BN + 1];
    const int tid = threadIdx.x;
    const int tx = tid % (BN / TN);
    const int ty = tid / (BN / TN);
    const int block_m = blockIdx.y * BM;
    const int block_n = blockIdx.x * BN;
    float acc[TM][TN];
#pragma unroll
    for (int i = 0; i < TM; i++)
#pragma unroll
        for (int j = 0; j < TN; j++) acc[i][j] = 0.f;

    for (int k0 = 0; k0 < K; k0 += BK) {
        for (int i = tid; i < BM * BK; i += THREADS) {
            int m = i / BK, kk = i % BK;
            int gm = block_m + m, gk = k0 + kk;
            As[kk][m] = (gm < M && gk < K) ? A[(size_t)gm * lda + gk] : 0.f;
        }
        for (int i = tid; i < BN * BK; i += THREADS) {
            int n = i / BK, kk = i % BK;
            int gn = block_n + n, gk = k0 + kk;
            Bs[kk][n] = (gn < N && gk < K) ? B[(size_t)gn * ldb + gk] : 0.f;
        }
        __syncthreads();
#pragma unroll
        for (int kk = 0; kk < BK; kk++) {
            float a[TM], b[TN];
#pragma unroll
            for (int i = 0; i < TM; i++) a[i] = As[kk][ty * TM + i];
#pragma unroll
            for (int j = 0; j < TN; j++) b[j] = Bs[kk][tx * TN + j];
#pragma unroll
            for (int i = 0; i < TM; i++)
#pragma unroll
                for (int j = 0; j < TN; j++) acc[i][j] += a[i] * b[j];
        }
        __syncthreads();
    }
#pragma unroll
    for (int i = 0; i < TM; i++) {
        int gm = block_m + ty * TM + i;
        if (gm >= M) continue;
#pragma unroll
        for (int j = 0; j < TN; j++) {
            int gn = block_n + tx * TN + j;
            if (gn >= N) continue;
            float v = acc[i][j];
            if (bias1) v += bias1[gn];
            if (bias2) v += bias2[gn];
            if (RELU) v = fmaxf(v, 0.f);
            C[(size_t)gm * ldc + gn] = v;
        }
    }
}

// ---------------------------------------------------------------------------
// xw transpose: xw[(b*T+t), g] -> xwT[(t*4096+g)*64 + b]
// ---------------------------------------------------------------------------
__global__ void xwt_transpose(const float* __restrict__ xw, float* __restrict__ xwT) {
    __shared__ float L[64][65];
    const int t = blockIdx.x;
    const int g0 = blockIdx.y * 64;
    const int tid = threadIdx.x;
    for (int u = 0; u < 16; u++) {
        int idx = u * 256 + tid;
        int b = idx >> 6, g = idx & 63;
        L[g][b] = xw[((size_t)b * TT + t) * 4096 + g0 + g];
    }
    __syncthreads();
    for (int u = 0; u < 16; u++) {
        int idx = u * 256 + tid;
        int g = idx >> 6, b = idx & 63;
        xwT[((size_t)t * 4096 + g0 + g) * 64 + b] = L[g][b];
    }
}

// ---------------------------------------------------------------------------
// LSTM per-step kernel v2. 512 blocks x 256 thr (2 blocks/CU, 2 waves/SIMD).
// Block owns 2 hidden slots x 4 gates (wave = gate). h staged through LDS in
// 16 KB chunks, double-buffered (one sync per chunk) with register prefetch.
// ---------------------------------------------------------------------------
__global__ void __launch_bounds__(256, 2)
lstm_step2(const float* __restrict__ xwT, const float* __restrict__ W_hh,
           const float* __restrict__ hin, float* __restrict__ hout,
           float* __restrict__ cst, float* __restrict__ hs, int step) {
    __shared__ float hl[2][4096];        // two 16 KB buffers: 64 k x 64 b
    __shared__ float part[4][2][64];     // [gate][hh_loc][b]
    const int tid = threadIdx.x;
    const int b = tid & 63;
    const int jw = __builtin_amdgcn_readfirstlane(tid >> 6);   // wave id = gate
    const int hh0 = blockIdx.x * 2;

    if (step > 0) {
        const float* __restrict__ Wbase = W_hh + ((size_t)jw * 1024 + hh0) * 1024;
        const float4* __restrict__ src = (const float4*)hin;
        float4 pf0 = src[tid];
        float4 pf1 = src[256 + tid];
        float4 pf2 = src[512 + tid];
        float4 pf3 = src[768 + tid];
        float acc0 = 0.f, acc1 = 0.f;
        for (int c = 0; c < 16; c++) {
            float4* dst = (float4*)hl[c & 1];
            dst[tid] = pf0; dst[256 + tid] = pf1;
            dst[512 + tid] = pf2; dst[768 + tid] = pf3;
            __syncthreads();                       // hl[c&1] ready; also protects
                                                   // next iter's write of other buf
            if (c < 15) {
                const float4* s2 = src + (c + 1) * 1024;
                pf0 = s2[tid]; pf1 = s2[256 + tid];
                pf2 = s2[512 + tid]; pf3 = s2[768 + tid];
            }
            const float* __restrict__ Wr = Wbase + c * 64;
            const float* __restrict__ hb = hl[c & 1];
#pragma unroll 8
            for (int kk = 0; kk < 64; kk++) {
                float hv = hb[kk * 64 + b];
                acc0 = fmaf(Wr[kk], hv, acc0);
                acc1 = fmaf(Wr[kk + 1024], hv, acc1);
            }
        }
        part[jw][0][b] = acc0;
        part[jw][1][b] = acc1;
        __syncthreads();
    }
    if (tid < 128) {
        const int i_p = tid >> 6;
        const int row = hh0 + i_p;
        const int idx = row * 64 + b;
        float g4[4];
#pragma unroll
        for (int j = 0; j < 4; j++) {
            float sum = xwT[((size_t)step * 4096 + j * 1024 + row) * 64 + b];
            if (step > 0) sum += part[j][i_p][b];
            g4[j] = sum;
        }
        float si = 1.f / (1.f + expf(-g4[0]));
        float sf = 1.f / (1.f + expf(-g4[1]));
        float tg = tanhf(g4[2]);
        float so = 1.f / (1.f + expf(-g4[3]));
        float cp = (step > 0) ? cst[idx] : 0.f;
        float cn = sf * cp + si * tg;
        cst[idx] = cn;
        float hn = so * tanhf(cn);
        hout[idx] = hn;
        hs[((size_t)step * BB + b) * HH + row] = hn;
    }
}

__global__ void qa2_kernel(const float* __restrict__ qa, const float* __restrict__ Wq2,
                           const float* __restrict__ bq2, float* __restrict__ out) {
    int tid = blockIdx.x * blockDim.x + threadIdx.x;
    if (tid >= BB * 2 * TT) return;
    int t = tid % TT;
    int bg = tid / TT;
    int g = bg & 1;
    const float* arow = qa + ((size_t)t * BB + (bg >> 1)) * 512;
    const float* wrow = Wq2 + g * 512;
    float acc = bq2[g];
    for (int o = 0; o < 512; o++) acc += wrow[o] * arow[o];
    out[tid] = acc;
}

__global__ void ia2_kernel(const float* __restrict__ ia, const float* __restrict__ Wi2,
                           const float* __restrict__ bi2, float* __restrict__ out) {
    int tid = blockIdx.x * blockDim.x + threadIdx.x;
    if (tid >= BB * 2 * SS) return;
    int s = tid % SS;
    int bg = tid / SS;
    int g = bg & 1;
    int b = bg >> 1;
    const float* arow = ia + ((size_t)b * SS + s) * 512;
    const float* wrow = Wi2 + g * 512;
    float acc = bi2[g];
    for (int o = 0; o < 512; o++) acc += wrow[o] * arow[o];
    out[tid] = acc;
}

__global__ void softmax_small(float* __restrict__ x, int rows, int len) {
    int r = blockIdx.x * blockDim.x + threadIdx.x;
    if (r >= rows) return;
    float* xr = x + (size_t)r * len;
    float mx = -1e30f;
    for (int i = 0; i < len; i++) mx = fmaxf(mx, xr[i]);
    float s = 0.f;
    for (int i = 0; i < len; i++) s += expf(xr[i] - mx);
    float inv = 1.f / s;
    for (int i = 0; i < len; i++) xr[i] = expf(xr[i] - mx) * inv;
}

__global__ void qfeat_kernel(const float* __restrict__ qatt, const float* __restrict__ hs,
                             float* __restrict__ qf) {
    int idx = blockIdx.x * blockDim.x + threadIdx.x;
    if (idx >= BB * 2048) return;
    int b = idx >> 11;
    int gh = idx & 2047;
    int g = gh >> 10;
    int hh = gh & 1023;
    float acc = 0.f;
    for (int t = 0; t < TT; t++)
        acc += qatt[((size_t)b * 2 + g) * TT + t] * hs[((size_t)t * BB + b) * HH + hh];
    qf[idx] = acc;
}

// ---------------------------------------------------------------------------
// Bucket build: scatter items into 16 overlapping bin-window buckets (once).
// Item i: h = h1x[i]; payload = img offset (s*FEAT+f) | sign<<31.
// ---------------------------------------------------------------------------
__global__ void bucket_build(const int* __restrict__ h1x, const int* __restrict__ s1x,
                             int* __restrict__ bcnt, int* __restrict__ bkh,
                             int* __restrict__ bkp) {
    int i = blockIdx.x * 256 + threadIdx.x;
    if (i >= NITEMS) return;
    int h = h1x[i];
    int f = i / SS, s = i - f * SS;
    int pay = (s * FEAT + f) | (s1x[i] << 31);
#pragma unroll
    for (int r = 0; r < FOLD_NR; r++) {
        int dd = h - r * FOLD_R;
        if (dd < 0) dd += D1;
        if (dd < FOLD_R + 196) {
            int pos = atomicAdd(&bcnt[r], 1);
            if (pos < BCAP) {
                bkh[r * BCAP + pos] = h;
                bkp[r * BCAP + pos] = pay;
            }
        }
    }
}

// ---------------------------------------------------------------------------
// MCB1 stage A v2: block (r, b) scans only bucket r (~6.6K items, not 100K),
// LDS-privatized scatter + FACTOR fold -> afold[b][t] fp32.
// ---------------------------------------------------------------------------
__global__ void sketch_fold2(const float* __restrict__ img_feat, const int* __restrict__ bcnt,
                             const int* __restrict__ bkh, const int* __restrict__ bkp,
                             float* __restrict__ afold) {
    __shared__ float sl[FOLD_R + 196];
    const int r = blockIdx.x;
    const int b = blockIdx.y;
    const int r0 = r * FOLD_R;
    for (int i = threadIdx.x; i < FOLD_R + 196; i += 256) sl[i] = 0.f;
    __syncthreads();
    const int n = min(bcnt[r], BCAP);
    const float* __restrict__ ib = img_feat + (size_t)b * NITEMS;
    for (int j = threadIdx.x; j < n; j += 256) {
        int h = bkh[r * BCAP + j];
        int pay = bkp[r * BCAP + j];
        int d = h - r0;
        if (d < 0) d += D1;
        float v = ib[pay & 0x7FFFFFFF];
        float val = ((unsigned)pay >> 31) ? v : -v;   // s1x=1 -> +1, 0 -> -1
        atomicAdd(&sl[d], val);
    }
    __syncthreads();
    float* ab = afold + (size_t)b * D1;
    for (int t = threadIdx.x; t < FOLD_R; t += 256) {
        int g = r0 + t;
        if (g >= D1) break;
        ab[g] = sl[t] + sl[t + 49] + sl[t + 98] + sl[t + 147] + sl[t + 196];
    }
}

// ---------------------------------------------------------------------------
// MCB1 stage B: transpose afold[b][t] -> atT[t][32 x half2], with wrap pad.
// f16 (not bf16): better precision AND enables v_fma_mix in the gather.
// ---------------------------------------------------------------------------
__global__ void transpose_f16(const float* __restrict__ afold, __half2* __restrict__ atT) {
    __shared__ float L[64][65];
    const int t0 = blockIdx.x * 64;
    const int tid = threadIdx.x;
    for (int c = 0; c < 16; c++) {
        int idx = c * 256 + tid;          // b*64 + i
        int b = idx >> 6, i = idx & 63;
        int t = t0 + i;
        int src_t = (t < D1) ? t : t - D1;
        L[i][b] = afold[(size_t)b * D1 + src_t];
    }
    __syncthreads();
    for (int c = 0; c < 8; c++) {
        int u = c * 256 + tid;            // t_loc*32 + qq
        int t_loc = u >> 5, qq = u & 31;
        int t = t0 + t_loc;
        if (t >= NROWS) continue;
        atT[(size_t)t * 32 + qq] =
            __halves2half2(__float2half_rn(L[t_loc][2 * qq]),
                           __float2half_rn(L[t_loc][2 * qq + 1]));
    }
}

// ---------------------------------------------------------------------------
// Bitonic sort of (h1q, index), 2048 elements, one block of 1024 threads.
// ---------------------------------------------------------------------------
__global__ void sort_pv(const int* __restrict__ h1q, int* __restrict__ pS,
                        int* __restrict__ permS) {
    __shared__ int k[2048], v[2048];
    const int t = threadIdx.x;
    k[t] = h1q[t];          v[t] = t;
    k[t + 1024] = h1q[t + 1024]; v[t + 1024] = t + 1024;
    for (int size = 2; size <= 2048; size <<= 1) {
        for (int stride = size >> 1; stride > 0; stride >>= 1) {
            __syncthreads();
            int pos = 2 * t - (t & (stride - 1));
            bool asc = ((pos & size) == 0);
            int a = k[pos], b = k[pos + stride];
            if ((a > b) == asc) {
                k[pos] = b; k[pos + stride] = a;
                int tmp = v[pos]; v[pos] = v[pos + stride]; v[pos + stride] = tmp;
            }
        }
    }
    __syncthreads();
    pS[t] = k[t]; pS[t + 1024] = k[t + 1024];
    permS[t] = v[t]; permS[t + 1024] = v[t + 1024];
}

// vTs[r][q] = half2( qf[2q][j]*sgn[j], qf[2q+1][j]*sgn[j] ), j = permS[r]
__global__ void vts_build(const float* __restrict__ qf, const int* __restrict__ s1q,
                          const int* __restrict__ permS, __half2* __restrict__ vTs) {
    int gid = blockIdx.x * blockDim.x + threadIdx.x;
    if (gid >= 2048 * 32) return;
    int r = gid >> 5, q = gid & 31;
    int j = permS[r];
    float sg = (float)(2 * s1q[j] - 1);
    vTs[gid] = __halves2half2(__float2half_rn(qf[(size_t)(2 * q) * 2048 + j] * sg),
                              __float2half_rn(qf[(size_t)(2 * q + 1) * 2048 + j] * sg));
}

__device__ __forceinline__ int lbound(const int* a, int x) {
    int lo = 0, hi = 2048;
    while (lo < hi) { int mid = (lo + hi) >> 1; if (a[mid] < x) lo = mid + 1; else hi = mid; }
    return lo;
}

// ---------------------------------------------------------------------------
// MCB1 gather v4: f16 sketch (v_fma_mix), 32 m per block -> 1568 blocks for
// latency hiding. iq[b][s][m] = sum_j v[b,j] * sketch[(245m+s-p_j) mod D1].
// ---------------------------------------------------------------------------
__global__ void __launch_bounds__(256, 8)
mcb1_gather4(const __half2* __restrict__ atT, const __half2* __restrict__ vTs,
             const int* __restrict__ pS, float* __restrict__ iq) {
    __shared__ int sp[2048];
    for (int i = threadIdx.x; i < 2048; i += 256) sp[i] = pS[i];
    __syncthreads();

    const int s = blockIdx.y;
    const int w = threadIdx.x >> 5;
    const int q = threadIdx.x & 31;
    const int m0 = blockIdx.x * 32 + w * 4;     // 4 m per thread-group
    const int m0c = (m0 <= 996) ? m0 : 996;
    const int tb0 = 245 * m0c + s;

    const __half2* __restrict__ atq = atT + q;
    const __half2* __restrict__ vtq = vTs + q;

    float accL[4], accH[4];
#pragma unroll
    for (int kk = 0; kk < 4; kk++) { accL[kk] = 0.f; accH[kk] = 0.f; }

    for (int c = 0; c < NP; c++) {
        const int A0 = c * WP;
        const int A1 = A0 + WP;
        int PL = tb0 - A1 + 1; if (PL < 0) PL += D1; if (PL >= D1) PL -= D1;
        int PH = tb0 - A0;     if (PH < 0) PH += D1; if (PH >= D1) PH -= D1;
        int r0a, r1a, r0b, r1b;
        if (PL <= PH) {
            r0a = lbound(sp, PL); r1a = lbound(sp, PH + 1);
            r0b = 0; r1b = 0;
        } else {
            r0a = lbound(sp, PL); r1a = 2048;
            r0b = 0; r1b = lbound(sp, PH + 1);
        }
#pragma unroll 1
        for (int seg = 0; seg < 2; seg++) {
            int rs = seg ? r0b : r0a;
            int re = seg ? r1b : r1a;
            for (int r = rs; r < re; r++) {
                int p = sp[r];
                int qe = (p <= tb0) ? -p : D1 - p;
                float2 vv = __half22float2(vtq[r * 32]);
                const __half2* row = atq + (size_t)(tb0 + qe) * 32;
#pragma unroll
                for (int kk = 0; kk < 4; kk++) {
                    float2 a = __half22float2(row[kk * 245 * 32]);
                    accL[kk] = fmaf(vv.x, a.x, accL[kk]);
                    accH[kk] = fmaf(vv.y, a.y, accH[kk]);
                }
            }
        }
    }

    if (m0 <= 996) {
        float* o0 = iq + ((size_t)(2 * q) * SS + s) * MOUT + m0;
        float* o1 = iq + ((size_t)(2 * q + 1) * SS + s) * MOUT + m0;
#pragma unroll
        for (int kk = 0; kk < 4; kk++) { o0[kk] = accL[kk]; o1[kk] = accH[kk]; }
    }
}

__global__ void ssqrt_l2norm(float* __restrict__ x, int n) {
    __shared__ float red[256];
    __shared__ float inv_s;
    int b = blockIdx.x;
    float* xb = x + (size_t)b * n;
    float ss = 0.f;
    for (int i = threadIdx.x; i < n; i += 256) {
        float v = xb[i];
        float y = (v >= 0.f) ? sqrtf(v) : -sqrtf(-v);
        xb[i] = y;
        ss += y * y;
    }
    red[threadIdx.x] = ss;
    __syncthreads();
    for (int s = 128; s > 0; s >>= 1) {
        if (threadIdx.x < s) red[threadIdx.x] += red[threadIdx.x + s];
        __syncthreads();
    }
    if (threadIdx.x == 0) inv_s = 1.f / fmaxf(sqrtf(red[0]), 1e-12f);
    __syncthreads();
    float inv = inv_s;
    for (int i = threadIdx.x; i < n; i += 256) xb[i] *= inv;
}

__global__ void ifeat_kernel(const float* __restrict__ iatt, const float* __restrict__ img_feat,
                             float* __restrict__ ifeat) {
    int idx = blockIdx.x * blockDim.x + threadIdx.x;
    if (idx >= BB * 4096) return;
    int b = idx >> 12;
    int gf = idx & 4095;
    int g = gf >> 11;
    int f = gf & 2047;
    float acc = 0.f;
    for (int s = 0; s < SS; s++)
        acc += iatt[((size_t)b * 2 + g) * SS + s] * img_feat[((size_t)b * SS + s) * FEAT + f];
    ifeat[idx] = acc;
}

__global__ void mcb2_scatter(const float* __restrict__ ifeat, const int* __restrict__ h2i,
                             const int* __restrict__ s2i, float* __restrict__ atil2) {
    int tid = blockIdx.x * blockDim.x + threadIdx.x;
    if (tid >= BB * 4096) return;
    int i = tid & 4095;
    int b = tid >> 12;
    float v = ifeat[tid] * (float)(2 * s2i[i] - 1);
    int p = h2i[i];
    float* ab = atil2 + (size_t)b * D2;
#pragma unroll
    for (int f = 0; f < 5; f++) {
        int t = p - f;
        if (t < 0) t += D2;
        atomicAdd(&ab[t], v);
    }
}

__global__ void mcb2_gather(const float* __restrict__ atil2, const float* __restrict__ qf,
                            const int* __restrict__ h2q, const int* __restrict__ s2q,
                            float* __restrict__ z) {
    __shared__ float sa[D2];
    __shared__ int sp[2048];
    __shared__ float sv[2048];
    int b = blockIdx.y;
    for (int i = threadIdx.x; i < D2; i += 256) sa[i] = atil2[(size_t)b * D2 + i];
    const float* qb = qf + (size_t)b * 2048;
    for (int j = threadIdx.x; j < 2048; j += 256) {
        sp[j] = h2q[j];
        sv[j] = qb[j] * (float)(2 * s2q[j] - 1);
    }
    __syncthreads();
    int m = blockIdx.x * 256 + threadIdx.x;
    if (m >= MOUT) return;
    int base = 5 * m + D2;
    float acc = 0.f;
#pragma unroll 4
    for (int j = 0; j < 2048; j++) {
        int addr = base - sp[j];
        if (addr >= D2) addr -= D2;
        acc += sv[j] * sa[addr];
    }
    z[(size_t)b * MOUT + m] = acc;
}

__global__ void softmax_rows(const float* __restrict__ logits, float* __restrict__ out, int n) {
    __shared__ float red[256];
    int b = blockIdx.x;
    const float* xr = logits + (size_t)b * n;
    float* orow = out + (size_t)b * n;
    float mx = -1e30f;
    for (int i = threadIdx.x; i < n; i += 256) mx = fmaxf(mx, xr[i]);
    red[threadIdx.x] = mx;
    __syncthreads();
    for (int s = 128; s > 0; s >>= 1) {
        if (threadIdx.x < s) red[threadIdx.x] = fmaxf(red[threadIdx.x], red[threadIdx.x + s]);
        __syncthreads();
    }
    mx = red[0];
    __syncthreads();
    float sum = 0.f;
    for (int i = threadIdx.x; i < n; i += 256) sum += expf(xr[i] - mx);
    red[threadIdx.x] = sum;
    __syncthreads();
    for (int s = 128; s > 0; s >>= 1) {
        if (threadIdx.x < s) red[threadIdx.x] += red[threadIdx.x + s];
        __syncthreads();
    }
    float inv = 1.f / red[0];
    for (int i = threadIdx.x; i < n; i += 256) orow[i] = expf(xr[i] - mx) * inv;
}

extern "C" void kernel_launch(void* const* d_in, const int* in_sizes, int n_in,
                              void* d_out, int out_size, void* d_ws, size_t ws_size,
                              hipStream_t stream) {
    (void)in_sizes; (void)n_in; (void)out_size; (void)ws_size;
    const float* ques = (const float*)d_in[0];
    const float* img  = (const float*)d_in[1];
    const float* W_ih = (const float*)d_in[2];
    const float* W_hh = (const float*)d_in[3];
    const float* b_ih = (const float*)d_in[4];
    const float* b_hh = (const float*)d_in[5];
    const float* Wq1  = (const float*)d_in[6];
    const float* bq1  = (const float*)d_in[7];
    const float* Wq2  = (const float*)d_in[8];
    const float* bq2  = (const float*)d_in[9];
    const float* Wi1  = (const float*)d_in[10];
    const float* bi1  = (const float*)d_in[11];
    const float* Wi2  = (const float*)d_in[12];
    const float* bi2  = (const float*)d_in[13];
    const float* Wp   = (const float*)d_in[14];
    const float* bpc  = (const float*)d_in[15];   // classifier bias
    const int* h1x = (const int*)d_in[16];
    const int* s1x = (const int*)d_in[17];
    const int* h1q = (const int*)d_in[18];
    const int* s1q = (const int*)d_in[19];
    const int* h2i = (const int*)d_in[20];
    const int* s2i = (const int*)d_in[21];
    const int* h2q = (const int*)d_in[22];
    const int* s2q = (const int*)d_in[23];
    float* out = (float*)d_out;

    // Workspace layout (4 B units). Region A (0..15,680,000) time-shared:
    // phase1 {xw,hs,hTa,hTb,cst,qa,qatt,xwT} -> afold -> phase2 smalls.
    float* ws = (float*)d_ws;
    float* xw    = ws;                  // 6,815,744
    float* hs    = ws + 6815744;        // 1,703,936
    float* hTa   = ws + 8519680;        // 65,536
    float* hTb   = ws + 8585216;        // 65,536
    float* cst   = ws + 8650752;        // 65,536
    float* qa    = ws + 10224640;       // 851,968
    float* qatt  = ws + 11076608;       // 4,096
    float* xwT   = ws + 11080704;       // 6,815,744 (dead before afold written)
    float* afold = ws;                  // 15,680,000 (written after lstm/qfeat)
    // phase2 smalls (inside region A, alive after transpose)
    float* iq     = ws;                 // 3,136,000
    float* ia     = ws + 3136000;       // 1,605,632
    float* iatt   = ws + 4741632;       // 8,192
    float* ifeat  = ws + 4749824;       // 262,144
    float* atil2  = ws + 5011968;       // 320,000
    float* z      = ws + 5331968;       // 64,000
    float* logits = ws + 5395968;       // 192,000
    // Region B/C (persistent across phases)
    __half2* atT   = (__half2*)(ws + 15680000);   // NROWS*32 half2 = 7,905,536 dwords
    float* qf      = ws + 15680000 + 7905536;     // 131,072
    __half2* vTs   = (__half2*)(qf + 131072);     // 65,536 dwords
    int* pS        = (int*)(ws + 15680000 + 7905536 + 131072 + 65536);  // 2,048
    int* permS     = pS + 2048;                   // 2,048
    int* bcnt      = permS + 2048;                // 64 (16 used)
    int* bkh       = bcnt + 64;                   // 16*8192 = 131,072
    int* bkp       = bkh + FOLD_NR * BCAP;        // 131,072  (end ~96.2 MB)

    // ---- independent preprocessing ----
    sort_pv<<<1, 1024, 0, stream>>>(h1q, pS, permS);
    (void)hipMemsetAsync(bcnt, 0, 64 * 4, stream);
    bucket_build<<<(NITEMS + 255) / 256, 256, 0, stream>>>(h1x, s1x, bcnt, bkh, bkp);

    // ---- LSTM ----
    {   // xW[(b*T+t), g] = ques(b,t,:) . W_ih(g,:) + b_ih + b_hh
        dim3 grid(4096 / 64, (BB * TT + 127) / 128);
        gemm_abt<128, 64, 16, 8, 4, false><<<grid, 256, 0, stream>>>(
            ques, W_ih, b_ih, b_hh, xw, BB * TT, 4 * HH, EE, EE, EE, 4 * HH);
    }
    {
        dim3 grid(TT, 64);
        xwt_transpose<<<grid, 256, 0, stream>>>(xw, xwT);
    }
    for (int t = 0; t < TT; t++) {
        float* hout = (t & 1) ? hTb : hTa;
        const float* hin = (t & 1) ? hTa : hTb;   // previous step's hout
        lstm_step2<<<512, 256, 0, stream>>>(xwT, W_hh, (t == 0) ? nullptr : hin,
                                            hout, cst, hs, t);
    }
    // ---- question attention ----
    {
        dim3 grid(512 / 64, (TT * BB + 127) / 128);
        gemm_abt<128, 64, 16, 8, 4, true><<<grid, 256, 0, stream>>>(
            hs, Wq1, bq1, nullptr, qa, TT * BB, 512, HH, HH, HH, 512);
    }
    qa2_kernel<<<(BB * 2 * TT + 255) / 256, 256, 0, stream>>>(qa, Wq2, bq2, qatt);
    softmax_small<<<1, 128, 0, stream>>>(qatt, BB * 2, TT);
    qfeat_kernel<<<(BB * 2048) / 256, 256, 0, stream>>>(qatt, hs, qf);
    // ---- MCB1: bucketed fold -> transpose(f16) -> phased gather ----
    {
        dim3 grid(FOLD_NR, BB);
        sketch_fold2<<<grid, 256, 0, stream>>>(img, bcnt, bkh, bkp, afold);
    }
    {
        int nblk = (NROWS + 63) / 64;
        transpose_f16<<<nblk, 256, 0, stream>>>(afold, atT);
    }
    vts_build<<<(2048 * 32) / 256, 256, 0, stream>>>(qf, s1q, permS, vTs);
    {
        dim3 grid(32, SS);
        mcb1_gather4<<<grid, 256, 0, stream>>>(atT, vTs, pS, iq);
    }
    ssqrt_l2norm<<<BB, 256, 0, stream>>>(iq, MOUT * SS);
    {
        dim3 grid(512 / 64, (BB * SS + 127) / 128);
        gemm_abt<128, 64, 16, 8, 4, true><<<grid, 256, 0, stream>>>(
            iq, Wi1, bi1, nullptr, ia, BB * SS, 512, MOUT, MOUT, MOUT, 512);
    }
    ia2_kernel<<<(BB * 2 * SS + 255) / 256, 256, 0, stream>>>(ia, Wi2, bi2, iatt);
    softmax_small<<<1, 128, 0, stream>>>(iatt, BB * 2, SS);
    ifeat_kernel<<<(BB * 4096) / 256, 256, 0, stream>>>(iatt, img, ifeat);
    // ---- MCB2 + classifier ----
    (void)hipMemsetAsync(atil2, 0, (size_t)BB * D2 * 4, stream);
    mcb2_scatter<<<(BB * 4096) / 256, 256, 0, stream>>>(ifeat, h2i, s2i, atil2);
    {
        dim3 grid(4, BB);
        mcb2_gather<<<grid, 256, 0, stream>>>(atil2, qf, h2q, s2q, z);
    }
    ssqrt_l2norm<<<BB, 256, 0, stream>>>(z, MOUT);
    {
        dim3 grid((VOCAB + 63) / 64, 4);
        gemm_abt<16, 64, 16, 2, 2, false><<<grid, 256, 0, stream>>>(
            z, Wp, bpc, nullptr, logits, BB, VOCAB, MOUT, MOUT, MOUT, VOCAB);
    }
    softmax_rows<<<BB, 256, 0, stream>>>(logits, out, VOCAB);
}